// Round 2
// baseline (691.896 us; speedup 1.0000x reference)
//
#include <hip/hip_runtime.h>
#include <math.h>

// Problem constants
#define NPIX  36864            // 192*192
#define PI2   6.28318530717958647692f

// Workspace layout (bytes)
#define TW_OFF    0            // 192 float2 twiddles e^{+2pi i n/192}
#define PCA_OFF   1536         // 576 float4 {a1, lf0, a2, th}
#define PCB_OFF   10752        // 576 float2 {fr, lsc}
#define W1F4_OFF  15360        // 64 float4 {w1[0..2], b1}
#define W2B_OFF   16384        // MFMA B-frags bf16 hi/lo: [kc][t][h][lane][8] = 49152 B
#define BN_OFF    65536        // 192 scale + 192 shift
#define IDX_OFF   67072        // 192*2 ints shifted intervals [o][i]{lo,hi}
#define M2_OFF    68608        // 64*64 M2 + 64 m1 floats (zeroed)
#define T1_OFF    85248        // 12*36864 float2 stage-1 DFT
#define XS_OFF    3624192      // 12*36864 float2 shifted spectrum
#define AH_OFF    7163136      // 36864 float2 ifftshifted A_tot
#define XF_OFF    7458048      // 64*36864 float xf (split path only)
#define WS_FUSED  7458048
#define WS_SPLIT  16895232

typedef __attribute__((ext_vector_type(8))) short short8;
typedef __attribute__((ext_vector_type(4))) float floatx4;

// ---------------- K0: precompute twiddles, params, W2 MFMA frags, intervals -
__global__ void k_pre(const float* freq, const float* theta, const float* sigma,
                      const float* f0, const float* theta0, const float* fbs,
                      const float* w1, const float* b1v, const float* w2,
                      char* ws) {
    float2* tw   = (float2*)(ws + TW_OFF);
    float4* pcA  = (float4*)(ws + PCA_OFF);
    float2* pcB  = (float2*)(ws + PCB_OFF);
    float4* w1f4 = (float4*)(ws + W1F4_OFF);
    unsigned short* w2b = (unsigned short*)(ws + W2B_OFF);
    int* idx = (int*)(ws + IDX_OFF);
    int tid = threadIdx.x;
    for (int n = tid; n < 192; n += blockDim.x) {
        float th = PI2 * (float)n / 192.0f;
        tw[n] = make_float2(cosf(th), sinf(th));
    }
    for (int t = tid; t < 576; t += blockDim.x) {
        int s = t / 192, rem = t % 192, o = rem / 3, i = rem % 3;
        float fr = freq[t], th = theta[t], sg = sigma[t], f0v = f0[t], th0 = theta0[t];
        float lg  = logf(sg / f0v);
        float a1  = -1.0f / (2.0f * lg * lg);
        float lf0 = logf(f0v);
        float a2  = -1.0f / (2.0f * th0 * th0);
        float lsc = -logf(PI2 * sg * sg);          // log(1/(2pi sg^2))
        int pidx = (s*3 + i)*64 + o;
        pcA[pidx] = make_float4(a1, lf0, a2, th);
        pcB[pidx] = make_float2(fr, lsc);
    }
    for (int t = tid; t < 64; t += blockDim.x)
        w1f4[t] = make_float4(w1[t*3+0], w1[t*3+1], w1[t*3+2], b1v[t]);
    // W2 B-fragments: entry e = ((kc*12+t)*2+h)*64+lane holds 8 bf16 (j=0..7)
    for (int u = tid; u < 24576; u += blockDim.x) {
        int j = u & 7; int v = u >> 3;
        int l = v & 63; v >>= 6;
        int hsel = v & 1; v >>= 1;
        int t = v % 12; int kc = v / 12;
        int k = kc*32 + (l>>4)*8 + j;
        int c = t*16 + (l & 15);
        float wv = w2[c*64 + k];
        unsigned ub = __builtin_bit_cast(unsigned, wv);
        unsigned short hi = (unsigned short)(ub >> 16);
        float vh = __builtin_bit_cast(float, ub & 0xFFFF0000u);
        unsigned short lo = (unsigned short)(__builtin_bit_cast(unsigned, wv - vh) >> 16);
        w2b[u] = hsel ? lo : hi;
    }
    for (int t = tid; t < 192; t += blockDim.x) {
        int lo = (int)floorf((fbs[t*2+0] + 1.0f) * 0.5f * 192.0f) - 96;
        int hi = (int)floorf((fbs[t*2+1] + 1.0f) * 0.5f * 192.0f) - 96;
        lo = max(0, min(96, lo));
        hi = max(0, min(96, hi));
        if (hi < lo) hi = lo;
        idx[t*2+0] = lo; idx[t*2+1] = hi;
    }
}

// ---------------- K1: stage-1 forward DFT over h (x real) -------------------
__global__ __launch_bounds__(192) void k_dft1(const float* x, char* ws) {
    __shared__ float2 twsh[192];
    const float2* tw = (const float2*)(ws + TW_OFF);
    float2* t1 = (float2*)(ws + T1_OFF);
    int tid = threadIdx.x;
    twsh[tid] = tw[tid];
    __syncthreads();
    int bi = blockIdx.x;
    int y0 = blockIdx.y * 4;
    int w  = tid;
    const float* xp = x + bi * NPIX;
    float2 acc[4];
#pragma unroll
    for (int d = 0; d < 4; d++) acc[d] = make_float2(0.f, 0.f);
    for (int h = 0; h < 192; h++) {
        float xv = xp[h*192 + w];
        int m = (h * y0) % 192;
#pragma unroll
        for (int d = 0; d < 4; d++) {
            float2 e = twsh[m];
            acc[d].x += xv * e.x;
            acc[d].y -= xv * e.y;
            m += h; if (m >= 192) m -= 192;
        }
    }
    float2* op = t1 + bi * NPIX;
#pragma unroll
    for (int d = 0; d < 4; d++) op[(y0 + d)*192 + w] = acc[d];
}

// ---------------- K2: stage-2 forward DFT over w + full fftshift write ------
__global__ __launch_bounds__(192) void k_dft2(char* ws) {
    __shared__ float2 twsh[192];
    __shared__ float2 row[192];
    const float2* tw = (const float2*)(ws + TW_OFF);
    const float2* t1 = (const float2*)(ws + T1_OFF);
    float2* Xs = (float2*)(ws + XS_OFF);
    int tid = threadIdx.x;
    int bi = blockIdx.x, y = blockIdx.y;
    twsh[tid] = tw[tid];
    row[tid]  = t1[bi*NPIX + y*192 + tid];
    __syncthreads();
    int kx = tid;
    float2 acc = make_float2(0.f, 0.f);
    int m = 0;
    for (int w = 0; w < 192; w++) {
        float2 t = row[w];
        float2 e = twsh[m];
        acc.x += t.x*e.x + t.y*e.y;
        acc.y += t.y*e.x - t.x*e.y;
        m += kx; if (m >= 192) m -= 192;
    }
    int b = bi / 3, i = bi % 3;
    int bs = (b + 2) & 3;
    int is = (i + 1) % 3;
    int ys = y + 96;  if (ys >= 192) ys -= 192;
    int ks = kx + 96; if (ks >= 192) ks -= 192;
    Xs[(bs*3 + is)*NPIX + ys*192 + ks] = acc;
}

// ---------------- K3: h1 mean + second moment (for BN stats) ----------------
__global__ __launch_bounds__(256) void k_stats(const float* w1, const float* b1v, char* ws) {
    __shared__ __align__(16) float h1t[64*68];
    const float2* Xs = (const float2*)(ws + XS_OFF);
    float* M2 = (float*)(ws + M2_OFF);
    int tid = threadIdx.x;
    int j  = tid & 63;
    int sq = tid >> 6;
    float wj0 = w1[j*3+0], wj1 = w1[j*3+1], wj2 = w1[j*3+2], bj = b1v[j];
    int tj = tid & 15, tk = tid >> 4;
    float acc[4][4], macc[4];
#pragma unroll
    for (int a = 0; a < 4; a++) { macc[a] = 0.f;
#pragma unroll
        for (int b = 0; b < 4; b++) acc[a][b] = 0.f; }
    for (int tile = blockIdx.x; tile < 2304; tile += gridDim.x) {
        int base = tile * 64;
        for (int ss = 0; ss < 16; ss++) {
            int sl = sq*16 + ss;
            int sidx = base + sl;
            int b = sidx / NPIX;
            int p = sidx - b*NPIX;
            const float2* xp = Xs + b*3*NPIX + p;
            float2 v0 = xp[0], v1 = xp[NPIX], v2 = xp[2*NPIX];
            float m0 = sqrtf(v0.x*v0.x + v0.y*v0.y);
            float m1 = sqrtf(v1.x*v1.x + v1.y*v1.y);
            float m2 = sqrtf(v2.x*v2.x + v2.y*v2.y);
            float h1 = bj + wj0*m0 + wj1*m1 + wj2*m2;
            h1t[sl*68 + j] = fmaxf(h1, 0.f);
        }
        __syncthreads();
        for (int s = 0; s < 64; s++) {
            float4 rj = *(const float4*)&h1t[s*68 + tj*4];
            float4 rk = *(const float4*)&h1t[s*68 + tk*4];
            float aj[4] = {rj.x, rj.y, rj.z, rj.w};
            float ak[4] = {rk.x, rk.y, rk.z, rk.w};
#pragma unroll
            for (int a = 0; a < 4; a++) {
                macc[a] += aj[a];
#pragma unroll
                for (int b = 0; b < 4; b++) acc[a][b] += aj[a]*ak[b];
            }
        }
        __syncthreads();
    }
#pragma unroll
    for (int a = 0; a < 4; a++)
#pragma unroll
        for (int b = 0; b < 4; b++)
            atomicAdd(&M2[(tj*4 + a)*64 + (tk*4 + b)], acc[a][b]);
    if (tk == 0)
#pragma unroll
        for (int a = 0; a < 4; a++) atomicAdd(&M2[4096 + tj*4 + a], macc[a]);
}

// ---------------- K4: BN scale/shift per channel ----------------------------
__global__ __launch_bounds__(192) void k_bn(const float* w2, const float* bnw,
                                            const float* bnb, char* ws) {
    __shared__ float w2sh[192*65];
    const float* M2 = (const float*)(ws + M2_OFF);
    const float* m1 = M2 + 4096;
    float* bnsc = (float*)(ws + BN_OFF);
    float* bnsh = bnsc + 192;
    int tid = threadIdx.x;
    for (int g = tid; g < 12288; g += 192) {
        int c = g >> 6, j = g & 63;
        w2sh[c*65 + j] = w2[g];
    }
    __syncthreads();
    const float invN = 1.0f / 147456.0f;
    int c = tid;
    const float* row = &w2sh[c*65];
    float d = 0.f;
    for (int jj = 0; jj < 64; jj++) d += row[jj] * m1[jj];
    d *= invN;
    float q = 0.f;
    for (int jj = 0; jj < 64; jj++) {
        float inner = 0.f;
        const float* m2r = M2 + jj*64;
        for (int k = 0; k < 64; k++) inner += row[k] * m2r[k];
        q += row[jj] * inner;
    }
    q *= invN;
    float var = q - d*d;
    float rstd = rsqrtf(var + 1e-5f);
    float scale = bnw[c] * rstd;
    bnsc[c] = scale;
    bnsh[c] = bnb[c] - d * scale;
}

// ---------------- K5: MFMA attention + gabor -> A_tot (ifftshifted) ---------
// wave = 16-sample group (4 pixels x 4 batches). A = h1 (m=sample), B = W2^T
// (n=channel, 12 tiles of 16). Split-bf16 x3 MFMA products ~ fp32 precision.
__global__ __launch_bounds__(256) void k_attn(char* ws) {
    __shared__ float4 P4[4096];                       // 64 KB param mirror
    const float2* Xs = (const float2*)(ws + XS_OFF);
    float2* Ah = (float2*)(ws + AH_OFF);
    {   // copy [PCA..BN) = 65536 B from ws into LDS
        const float4* src = (const float4*)(ws + PCA_OFF);
        for (int u = threadIdx.x; u < 4096; u += 256) P4[u] = src[u];
    }
    __syncthreads();
    const float4* pcA4  = (const float4*)P4;                          // 576
    const float2* pcB2  = (const float2*)((const char*)P4 + 9216);    // 576
    const float4* w1f4p = (const float4*)((const char*)P4 + 13824);   // 64
    const char*   w2bs  = (const char*)P4 + 14848;                    // frags
    const float*  bnA   = (const float*)((const char*)P4 + 64000);    // 384

    int tid = threadIdx.x;
    int wave = tid >> 6, lane = tid & 63;
    int cl = lane & 15, q = lane >> 4;

    union AB { short8 v; unsigned short u[8]; };

    for (int it = 0; it < 6; it++) {
        int g = blockIdx.x * 24 + wave * 6 + it;     // 384 blocks * 24 = 9216
        int pix0 = g * 4;
        // ---- phase 1: h1 for sample m = cl, build A-frags (hi/lo bf16) ----
        int m = cl;
        int pb = pix0 + (m >> 2);
        int bb = m & 3;
        float2 q0 = Xs[(bb*3+0)*NPIX + pb];
        float2 q1 = Xs[(bb*3+1)*NPIX + pb];
        float2 q2 = Xs[(bb*3+2)*NPIX + pb];
        float mg0 = sqrtf(q0.x*q0.x + q0.y*q0.y);
        float mg1 = sqrtf(q1.x*q1.x + q1.y*q1.y);
        float mg2 = sqrtf(q2.x*q2.x + q2.y*q2.y);
        AB ah[2], al[2];
#pragma unroll
        for (int kc = 0; kc < 2; kc++)
#pragma unroll
            for (int j = 0; j < 8; j++) {
                int k = kc*32 + q*8 + j;
                float4 wf = w1f4p[k];
                float hv = fmaxf(wf.w + wf.x*mg0 + wf.y*mg1 + wf.z*mg2, 0.f);
                unsigned ub = __builtin_bit_cast(unsigned, hv);
                ah[kc].u[j] = (unsigned short)(ub >> 16);
                float vh = __builtin_bit_cast(float, ub & 0xFFFF0000u);
                al[kc].u[j] = (unsigned short)(__builtin_bit_cast(unsigned, hv - vh) >> 16);
            }
        // ---- phase 2: GEMM 12 c-tiles, K=64 (2 chunks), 3-product split ----
        floatx4 acc[12];
#pragma unroll
        for (int t = 0; t < 12; t++) {
            floatx4 a = {0.f, 0.f, 0.f, 0.f};
#pragma unroll
            for (int kc = 0; kc < 2; kc++) {
                int ob = (((kc*12 + t)*2)*64 + lane)*16;
                short8 bh = *(const short8*)(w2bs + ob);
                short8 bl = *(const short8*)(w2bs + ob + 1024);
                a = __builtin_amdgcn_mfma_f32_16x16x32_bf16(ah[kc].v, bh, a, 0, 0, 0);
                a = __builtin_amdgcn_mfma_f32_16x16x32_bf16(al[kc].v, bh, a, 0, 0, 0);
                a = __builtin_amdgcn_mfma_f32_16x16x32_bf16(ah[kc].v, bl, a, 0, 0, 0);
            }
            acc[t] = a;
        }
        // C layout: n = cl -> c = t*16+cl ; m = q*4+r -> pixel pix0+q, batch r
        // ---- BN + softmax over 192 channels (in-lane 12 x cross-lane 16) ---
#pragma unroll
        for (int t = 0; t < 12; t++) {
            int c = t*16 + cl;
            float sc_ = bnA[c], sh_ = bnA[192 + c];
#pragma unroll
            for (int r = 0; r < 4; r++) acc[t][r] = acc[t][r]*sc_ + sh_;
        }
        float mx[4] = {-3.4e38f, -3.4e38f, -3.4e38f, -3.4e38f};
#pragma unroll
        for (int t = 0; t < 12; t++)
#pragma unroll
            for (int r = 0; r < 4; r++) mx[r] = fmaxf(mx[r], acc[t][r]);
#pragma unroll
        for (int sh = 1; sh < 16; sh <<= 1)
#pragma unroll
            for (int r = 0; r < 4; r++) mx[r] = fmaxf(mx[r], __shfl_xor(mx[r], sh));
        float sm[4] = {0.f, 0.f, 0.f, 0.f};
#pragma unroll
        for (int t = 0; t < 12; t++)
#pragma unroll
            for (int r = 0; r < 4; r++) {
                float e = __expf(acc[t][r] - mx[r]);
                acc[t][r] = e; sm[r] += e;
            }
#pragma unroll
        for (int sh = 1; sh < 16; sh <<= 1)
#pragma unroll
            for (int r = 0; r < 4; r++) sm[r] += __shfl_xor(sm[r], sh);
        float inv0 = 1.0f/sm[0], inv1 = 1.0f/sm[1], inv2 = 1.0f/sm[2], inv3 = 1.0f/sm[3];
#pragma unroll
        for (int t = 0; t < 12; t++) {
            acc[t][0] *= inv0; acc[t][1] *= inv1; acc[t][2] *= inv2; acc[t][3] *= inv3;
        }
        // ---- gabor + attention-weighted filter accumulation ----------------
        int pixE = pix0 + q;
        int hh = pixE / 192, ww = pixE - hh*192;
        float yy = -1.0f + (float)hh * (2.0f/191.0f);
        float xx = -1.0f + (float)ww * (2.0f/191.0f);
        float rr = sqrtf(xx*xx + yy*yy + 1e-6f);
        float lr = __logf(rr);
        float phi = atan2f(yy, xx);
        float Wr[4][3];
#pragma unroll
        for (int r = 0; r < 4; r++) { Wr[r][0] = 0.f; Wr[r][1] = 0.f; Wr[r][2] = 0.f; }
#pragma unroll
        for (int t = 0; t < 12; t++) {
            int c = t*16 + cl;
            int s = c >> 6, o = c & 63;
#pragma unroll
            for (int i = 0; i < 3; i++) {
                int pidx = (s*3 + i)*64 + o;
                float4 pa = pcA4[pidx];
                float2 pbv = pcB2[pidx];
                float dl = lr - pa.y, dp = phi - pa.w;
                float gv = __expf(pa.x*dl*dl + pa.z*dp*dp + pbv.y) * __cosf(pbv.x*rr);
                Wr[0][i] += acc[t][0]*gv;
                Wr[1][i] += acc[t][1]*gv;
                Wr[2][i] += acc[t][2]*gv;
                Wr[3][i] += acc[t][3]*gv;
            }
        }
        float are = 0.f, aim = 0.f;
#pragma unroll
        for (int r = 0; r < 4; r++)
#pragma unroll
            for (int i = 0; i < 3; i++) {
                float2 xv = Xs[(r*3+i)*NPIX + pixE];
                are += Wr[r][i]*xv.x;
                aim += Wr[r][i]*xv.y;
            }
#pragma unroll
        for (int sh = 1; sh < 16; sh <<= 1) {
            are += __shfl_xor(are, sh);
            aim += __shfl_xor(aim, sh);
        }
        if (cl == 0) {
            int hs = hh + 96; if (hs >= 192) hs -= 192;
            int wsx = ww + 96; if (wsx >= 192) wsx -= 192;
            Ah[hs*192 + wsx] = make_float2(are, aim);
        }
    }
}

// ---------------- K6a: interval-masked IDFT -> xf (split path) --------------
__global__ __launch_bounds__(192) void k_ifft(char* ws) {
    __shared__ float2 twsh[192];
    __shared__ float2 Ssh[3][96];
    __shared__ int iL[3], iH[3];
    const float2* tw = (const float2*)(ws + TW_OFF);
    const int* idx = (const int*)(ws + IDX_OFF);
    const float2* Ah = (const float2*)(ws + AH_OFF);
    float* xf = (float*)(ws + XF_OFF);
    int tid = threadIdx.x;
    int y = blockIdx.x;
    int o = blockIdx.y;
    int op = (o + 32) & 63;
    twsh[tid] = tw[tid];
    if (tid < 3) { iL[tid] = idx[(op*3 + tid)*2]; iH[tid] = idx[(op*3 + tid)*2 + 1]; }
    __syncthreads();
    int l0 = iL[0], u0 = iH[0], l1 = iL[1], u1 = iH[1], l2 = iL[2], u2 = iH[2];
    int n0 = u0 - l0, n1 = u1 - l1, n2 = u2 - l2;
    int p1 = n0 + n1, T = p1 + n2;
    float2 stepy = twsh[y];
    for (int t = tid; t < T; t += 192) {
        int i, off, lo, hi;
        if (t < n0)      { i = 0; off = t;      lo = l0; hi = u0; }
        else if (t < p1) { i = 1; off = t - n0; lo = l1; hi = u1; }
        else             { i = 2; off = t - p1; lo = l2; hi = u2; }
        int wq = lo + off;
        float2 e = twsh[(lo * y) % 192];
        float sx = 0.f, sy = 0.f;
        for (int hq = lo; hq < hi; hq++) {
            float2 a = Ah[hq*192 + wq];
            sx += a.x*e.x - a.y*e.y;
            sy += a.x*e.y + a.y*e.x;
            float ex = e.x*stepy.x - e.y*stepy.y;
            e.y = e.x*stepy.y + e.y*stepy.x;
            e.x = ex;
        }
        Ssh[i][off] = make_float2(sx, sy);
    }
    __syncthreads();
    int col = tid;
    float2 stepc = twsh[col];
    float accre = 0.f;
#pragma unroll
    for (int i = 0; i < 3; i++) {
        int lo = iL[i];
        int wi = iH[i] - lo;
        float2 e = twsh[(lo * col) % 192];
        for (int off = 0; off < wi; off++) {
            float2 S = Ssh[i][off];
            accre += S.x*e.x - S.y*e.y;
            float ex = e.x*stepc.x - e.y*stepc.y;
            e.y = e.x*stepc.y + e.y*stepc.x;
            e.x = ex;
        }
    }
    xf[o*NPIX + y*192 + col] = accre * (1.0f / 36864.0f);
}

// ---------------- K6b: 3x3 conv (sgpr weights) + mix (split path) -----------
__global__ __launch_bounds__(192) void k_conv(const float* x, const float* convw,
                                              const float* mixp, const float* xf,
                                              float* out) {
    int col = threadIdx.x;
    int y = blockIdx.x;
    int b = blockIdx.y;
    float xv[27];
#pragma unroll
    for (int i = 0; i < 3; i++)
#pragma unroll
        for (int dy = 0; dy < 3; dy++)
#pragma unroll
            for (int dx = 0; dx < 3; dx++) {
                int yq = y + dy - 1, xq = col + dx - 1;
                bool ok = (yq >= 0) & (yq < 192) & (xq >= 0) & (xq < 192);
                xv[(i*3 + dy)*3 + dx] = ok ? x[(b*3+i)*NPIX + yq*192 + xq] : 0.f;
            }
    float mixv = mixp[0];
    float onem = 1.0f - mixv;
    for (int o = 0; o < 64; o++) {
        float s = 0.f;
#pragma unroll
        for (int c = 0; c < 27; c++) s += xv[c] * convw[o*27 + c];
        float xfv = xf[o*NPIX + y*192 + col];
        out[((b*64 + o)*192 + y)*192 + col] = mixv*xfv + onem*s;
    }
}

// ---------------- K6 (fallback): fused IDFT + conv + mix --------------------
__global__ __launch_bounds__(192) void k_final(const float* x, const float* convw,
                                               const float* mixp, float* out, char* ws) {
    __shared__ float2 twsh[192];
    __shared__ float2 Ssh[3][96];
    __shared__ float cwsh[27];
    __shared__ int iL[3], iH[3];
    const float2* tw = (const float2*)(ws + TW_OFF);
    const int* idx = (const int*)(ws + IDX_OFF);
    const float2* Ah = (const float2*)(ws + AH_OFF);
    int tid = threadIdx.x;
    int y = blockIdx.x;
    int o = blockIdx.y;
    int op = (o + 32) & 63;
    twsh[tid] = tw[tid];
    if (tid < 27) cwsh[tid] = convw[o*27 + tid];
    if (tid < 3) { iL[tid] = idx[(op*3 + tid)*2]; iH[tid] = idx[(op*3 + tid)*2 + 1]; }
    __syncthreads();
    int l0 = iL[0], u0 = iH[0], l1 = iL[1], u1 = iH[1], l2 = iL[2], u2 = iH[2];
    int n0 = u0 - l0, n1 = u1 - l1, n2 = u2 - l2;
    int p1 = n0 + n1, T = p1 + n2;
    for (int t = tid; t < T; t += 192) {
        int i, off, lo, hi;
        if (t < n0)      { i = 0; off = t;      lo = l0; hi = u0; }
        else if (t < p1) { i = 1; off = t - n0; lo = l1; hi = u1; }
        else             { i = 2; off = t - p1; lo = l2; hi = u2; }
        int wq = lo + off;
        float sx = 0.f, sy = 0.f;
        int m = (lo * y) % 192;
        for (int hq = lo; hq < hi; hq++) {
            float2 a = Ah[hq*192 + wq];
            float2 e = twsh[m];
            sx += a.x*e.x - a.y*e.y;
            sy += a.x*e.y + a.y*e.x;
            m += y; if (m >= 192) m -= 192;
        }
        Ssh[i][off] = make_float2(sx, sy);
    }
    __syncthreads();
    int col = tid;
    float accre = 0.f;
#pragma unroll
    for (int i = 0; i < 3; i++) {
        int lo = iL[i];
        int wi = iH[i] - lo;
        int m = (lo * col) % 192;
        for (int off = 0; off < wi; off++) {
            float2 S = Ssh[i][off];
            float2 e = twsh[m];
            accre += S.x*e.x - S.y*e.y;
            m += col; if (m >= 192) m -= 192;
        }
    }
    float xfv = accre * (1.0f / 36864.0f);
    float mixv = mixp[0];
    float onem = 1.0f - mixv;
#pragma unroll
    for (int b = 0; b < 4; b++) {
        float s = 0.f;
#pragma unroll
        for (int i = 0; i < 3; i++) {
            const float* xp = x + (b*3 + i)*NPIX;
#pragma unroll
            for (int dy = -1; dy <= 1; dy++) {
                int yq = y + dy;
                if (yq < 0 || yq >= 192) continue;
                const float* rowp = xp + yq*192;
#pragma unroll
                for (int dx = -1; dx <= 1; dx++) {
                    int xq = col + dx;
                    if (xq < 0 || xq >= 192) continue;
                    s += rowp[xq] * cwsh[i*9 + (dy+1)*3 + (dx+1)];
                }
            }
        }
        out[((b*64 + o)*192 + y)*192 + col] = mixv*xfv + onem*s;
    }
}

extern "C" void kernel_launch(void* const* d_in, const int* in_sizes, int n_in,
                              void* d_out, int out_size, void* d_ws, size_t ws_size,
                              hipStream_t stream) {
    const float* x      = (const float*)d_in[0];
    const float* freq   = (const float*)d_in[1];
    const float* theta  = (const float*)d_in[2];
    const float* sigma  = (const float*)d_in[3];
    const float* f0     = (const float*)d_in[4];
    const float* theta0 = (const float*)d_in[5];
    const float* aw1    = (const float*)d_in[6];
    const float* ab1    = (const float*)d_in[7];
    const float* aw2    = (const float*)d_in[8];
    // d_in[9] = attn_b2: cancelled exactly by BN mean-subtraction, unused
    const float* bnw    = (const float*)d_in[10];
    const float* bnb    = (const float*)d_in[11];
    const float* mixp   = (const float*)d_in[12];
    const float* convw  = (const float*)d_in[13];
    const float* fbs    = (const float*)d_in[14];
    float* out = (float*)d_out;
    char* ws = (char*)d_ws;
    if (ws_size < (size_t)WS_FUSED) return;

    hipMemsetAsync(ws + M2_OFF, 0, 16640, stream);
    k_pre  <<<1, 256, 0, stream>>>(freq, theta, sigma, f0, theta0, fbs,
                                   aw1, ab1, aw2, ws);
    k_dft1 <<<dim3(12, 48),  192, 0, stream>>>(x, ws);
    k_dft2 <<<dim3(12, 192), 192, 0, stream>>>(ws);
    k_stats<<<288, 256, 0, stream>>>(aw1, ab1, ws);
    k_bn   <<<1, 192, 0, stream>>>(aw2, bnw, bnb, ws);
    k_attn <<<384, 256, 0, stream>>>(ws);
    if (ws_size >= (size_t)WS_SPLIT) {
        k_ifft <<<dim3(192, 64), 192, 0, stream>>>(ws);
        k_conv <<<dim3(192, 4),  192, 0, stream>>>(x, convw, mixp,
                                                   (const float*)(ws + XF_OFF), out);
    } else {
        k_final<<<dim3(192, 64), 192, 0, stream>>>(x, convw, mixp, out, ws);
    }
}

// Round 3
// 434.491 us; speedup vs baseline: 1.5924x; 1.5924x over previous
//
#include <hip/hip_runtime.h>
#include <math.h>

// Problem constants
#define NPIX  36864            // 192*192
#define PI2   6.28318530717958647692f

// Workspace layout (bytes)
#define TW_OFF    0            // 192 float2 twiddles e^{+2pi i n/192}
#define PCA_OFF   1536         // 576 float4 {a1, lf0, a2, th}
#define PCB_OFF   10752        // 576 float2 {fr, lsc}
#define W1F4_OFF  15360        // 64 float4 {w1[0..2], b1}
#define W2B_OFF   16384        // MFMA B-frags bf16 hi/lo: [kc][t][h][lane][8] = 49152 B
#define BN_OFF    65536        // 192 scale + 192 shift
#define IDX_OFF   67072        // 192*2 ints shifted intervals [o][i]{lo,hi}
#define M2_OFF    68608        // 64*64 M2 + 64 m1 floats (zeroed)
#define T1_OFF    85248        // 12*36864 float2 stage-1 DFT
#define XS_OFF    3624192      // 12*36864 float2 shifted spectrum
#define AH_OFF    7163136      // 36864 float2 ifftshifted A_tot
#define XF_OFF    7458048      // 64*36864 float xf (split path only)
#define WS_FUSED  7458048
#define WS_SPLIT  16895232

typedef __attribute__((ext_vector_type(8))) short short8;
typedef __attribute__((ext_vector_type(4))) float floatx4;

// ---------------- K0: precompute twiddles, params, W2 MFMA frags, intervals -
__global__ void k_pre(const float* freq, const float* theta, const float* sigma,
                      const float* f0, const float* theta0, const float* fbs,
                      const float* w1, const float* b1v, const float* w2,
                      char* ws) {
    float2* tw   = (float2*)(ws + TW_OFF);
    float4* pcA  = (float4*)(ws + PCA_OFF);
    float2* pcB  = (float2*)(ws + PCB_OFF);
    float4* w1f4 = (float4*)(ws + W1F4_OFF);
    unsigned short* w2b = (unsigned short*)(ws + W2B_OFF);
    int* idx = (int*)(ws + IDX_OFF);
    int tid = threadIdx.x;
    for (int n = tid; n < 192; n += blockDim.x) {
        float th = PI2 * (float)n / 192.0f;
        tw[n] = make_float2(cosf(th), sinf(th));
    }
    for (int t = tid; t < 576; t += blockDim.x) {
        int s = t / 192, rem = t % 192, o = rem / 3, i = rem % 3;
        float fr = freq[t], th = theta[t], sg = sigma[t], f0v = f0[t], th0 = theta0[t];
        float lg  = logf(sg / f0v);
        float a1  = -1.0f / (2.0f * lg * lg);
        float lf0 = logf(f0v);
        float a2  = -1.0f / (2.0f * th0 * th0);
        float lsc = -logf(PI2 * sg * sg);          // log(1/(2pi sg^2))
        int pidx = (s*3 + i)*64 + o;
        pcA[pidx] = make_float4(a1, lf0, a2, th);
        pcB[pidx] = make_float2(fr, lsc);
    }
    for (int t = tid; t < 64; t += blockDim.x)
        w1f4[t] = make_float4(w1[t*3+0], w1[t*3+1], w1[t*3+2], b1v[t]);
    // W2 B-fragments: entry e = ((kc*12+t)*2+h)*64+lane holds 8 bf16 (j=0..7)
    for (int u = tid; u < 24576; u += blockDim.x) {
        int j = u & 7; int v = u >> 3;
        int l = v & 63; v >>= 6;
        int hsel = v & 1; v >>= 1;
        int t = v % 12; int kc = v / 12;
        int k = kc*32 + (l>>4)*8 + j;
        int c = t*16 + (l & 15);
        float wv = w2[c*64 + k];
        unsigned ub = __builtin_bit_cast(unsigned, wv);
        unsigned short hi = (unsigned short)(ub >> 16);
        float vh = __builtin_bit_cast(float, ub & 0xFFFF0000u);
        unsigned short lo = (unsigned short)(__builtin_bit_cast(unsigned, wv - vh) >> 16);
        w2b[u] = hsel ? lo : hi;
    }
    for (int t = tid; t < 192; t += blockDim.x) {
        int lo = (int)floorf((fbs[t*2+0] + 1.0f) * 0.5f * 192.0f) - 96;
        int hi = (int)floorf((fbs[t*2+1] + 1.0f) * 0.5f * 192.0f) - 96;
        lo = max(0, min(96, lo));
        hi = max(0, min(96, hi));
        if (hi < lo) hi = lo;
        idx[t*2+0] = lo; idx[t*2+1] = hi;
    }
}

// ---------------- K1: stage-1 forward DFT over h (x real) -------------------
__global__ __launch_bounds__(192) void k_dft1(const float* x, char* ws) {
    __shared__ float2 twsh[192];
    const float2* tw = (const float2*)(ws + TW_OFF);
    float2* t1 = (float2*)(ws + T1_OFF);
    int tid = threadIdx.x;
    twsh[tid] = tw[tid];
    __syncthreads();
    int bi = blockIdx.x;
    int y0 = blockIdx.y * 4;
    int w  = tid;
    const float* xp = x + bi * NPIX;
    float2 acc[4];
#pragma unroll
    for (int d = 0; d < 4; d++) acc[d] = make_float2(0.f, 0.f);
    for (int h = 0; h < 192; h++) {
        float xv = xp[h*192 + w];
        int m = (h * y0) % 192;
#pragma unroll
        for (int d = 0; d < 4; d++) {
            float2 e = twsh[m];
            acc[d].x += xv * e.x;
            acc[d].y -= xv * e.y;
            m += h; if (m >= 192) m -= 192;
        }
    }
    float2* op = t1 + bi * NPIX;
#pragma unroll
    for (int d = 0; d < 4; d++) op[(y0 + d)*192 + w] = acc[d];
}

// ---------------- K2: stage-2 forward DFT over w + full fftshift write ------
// Twiddle via register rotation (re-seeded every 32 steps) - no per-lane LDS.
__global__ __launch_bounds__(192) void k_dft2(char* ws) {
    __shared__ float2 twsh[192];
    __shared__ float2 row[192];
    const float2* tw = (const float2*)(ws + TW_OFF);
    const float2* t1 = (const float2*)(ws + T1_OFF);
    float2* Xs = (float2*)(ws + XS_OFF);
    int tid = threadIdx.x;
    int bi = blockIdx.x, y = blockIdx.y;
    twsh[tid] = tw[tid];
    row[tid]  = t1[bi*NPIX + y*192 + tid];
    __syncthreads();
    int kx = tid;
    float2 st = twsh[kx];
    float2 acc = make_float2(0.f, 0.f);
#pragma unroll 1
    for (int w0 = 0; w0 < 192; w0 += 32) {
        float2 e = twsh[(w0 * kx) % 192];
#pragma unroll
        for (int w = 0; w < 32; w++) {
            float2 t = row[w0 + w];
            acc.x += t.x*e.x + t.y*e.y;          // t * conj(e)
            acc.y += t.y*e.x - t.x*e.y;
            float ex = e.x*st.x - e.y*st.y;
            e.y = e.x*st.y + e.y*st.x;
            e.x = ex;
        }
    }
    int b = bi / 3, i = bi % 3;
    int bs = (b + 2) & 3;
    int is = (i + 1) % 3;
    int ys = y + 96;  if (ys >= 192) ys -= 192;
    int ks = kx + 96; if (ks >= 192) ks -= 192;
    Xs[(bs*3 + is)*NPIX + ys*192 + ks] = acc;
}

// ---------------- K3: h1 mean + second moment (for BN stats) ----------------
__global__ __launch_bounds__(256) void k_stats(const float* w1, const float* b1v, char* ws) {
    __shared__ __align__(16) float h1t[64*68];
    const float2* Xs = (const float2*)(ws + XS_OFF);
    float* M2 = (float*)(ws + M2_OFF);
    int tid = threadIdx.x;
    int j  = tid & 63;
    int sq = tid >> 6;
    float wj0 = w1[j*3+0], wj1 = w1[j*3+1], wj2 = w1[j*3+2], bj = b1v[j];
    int tj = tid & 15, tk = tid >> 4;
    float acc[4][4], macc[4];
#pragma unroll
    for (int a = 0; a < 4; a++) { macc[a] = 0.f;
#pragma unroll
        for (int b = 0; b < 4; b++) acc[a][b] = 0.f; }
    for (int tile = blockIdx.x; tile < 2304; tile += gridDim.x) {
        int base = tile * 64;
        for (int ss = 0; ss < 16; ss++) {
            int sl = sq*16 + ss;
            int sidx = base + sl;
            int b = sidx / NPIX;
            int p = sidx - b*NPIX;
            const float2* xp = Xs + b*3*NPIX + p;
            float2 v0 = xp[0], v1 = xp[NPIX], v2 = xp[2*NPIX];
            float m0 = sqrtf(v0.x*v0.x + v0.y*v0.y);
            float m1 = sqrtf(v1.x*v1.x + v1.y*v1.y);
            float m2 = sqrtf(v2.x*v2.x + v2.y*v2.y);
            float h1 = bj + wj0*m0 + wj1*m1 + wj2*m2;
            h1t[sl*68 + j] = fmaxf(h1, 0.f);
        }
        __syncthreads();
        for (int s = 0; s < 64; s++) {
            float4 rj = *(const float4*)&h1t[s*68 + tj*4];
            float4 rk = *(const float4*)&h1t[s*68 + tk*4];
            float aj[4] = {rj.x, rj.y, rj.z, rj.w};
            float ak[4] = {rk.x, rk.y, rk.z, rk.w};
#pragma unroll
            for (int a = 0; a < 4; a++) {
                macc[a] += aj[a];
#pragma unroll
                for (int b = 0; b < 4; b++) acc[a][b] += aj[a]*ak[b];
            }
        }
        __syncthreads();
    }
#pragma unroll
    for (int a = 0; a < 4; a++)
#pragma unroll
        for (int b = 0; b < 4; b++)
            atomicAdd(&M2[(tj*4 + a)*64 + (tk*4 + b)], acc[a][b]);
    if (tk == 0)
#pragma unroll
        for (int a = 0; a < 4; a++) atomicAdd(&M2[4096 + tj*4 + a], macc[a]);
}

// ---------------- K4: BN scale/shift, one block per channel -----------------
__global__ __launch_bounds__(64) void k_bn(const float* w2, const float* bnw,
                                           const float* bnb, char* ws) {
    const float* M2 = (const float*)(ws + M2_OFF);
    const float* m1 = M2 + 4096;
    float* bnsc = (float*)(ws + BN_OFF);
    float* bnsh = bnsc + 192;
    int c = blockIdx.x;
    int jj = threadIdx.x;
    const float* row = w2 + c*64;
    float rj = row[jj];
    float inner = 0.f;
    const float* m2r = M2 + jj*64;
    for (int k = 0; k < 64; k++) inner += row[k] * m2r[k];
    float qpart = rj * inner;
    float dpart = rj * m1[jj];
#pragma unroll
    for (int sh = 32; sh >= 1; sh >>= 1) {
        qpart += __shfl_xor(qpart, sh);
        dpart += __shfl_xor(dpart, sh);
    }
    if (jj == 0) {
        const float invN = 1.0f / 147456.0f;
        float d = dpart * invN;
        float qv = qpart * invN;
        float var = qv - d*d;
        float rstd = rsqrtf(var + 1e-5f);
        float scale = bnw[c] * rstd;
        bnsc[c] = scale;
        bnsh[c] = bnb[c] - d * scale;
    }
}

// ---------------- K5: MFMA attention + gabor -> A_tot (online softmax) ------
// wave = 16-sample group (4 pixels x 4 batches). Streaming over 12 c-tiles;
// per-tile acc dies immediately -> no spills. exp without max-subtract is
// safe: BN output is ~N(0,1)*bn_w+bn_b.
__global__ __launch_bounds__(256) void k_attn(char* ws) {
    __shared__ __align__(16) char W2L[49152];
    __shared__ float4 w1L[64];
    const float2* Xs = (const float2*)(ws + XS_OFF);
    const float4* pcA4 = (const float4*)(ws + PCA_OFF);
    const float2* pcB2 = (const float2*)(ws + PCB_OFF);
    const float* bnA = (const float*)(ws + BN_OFF);   // [0..192) scale, [192..384) shift
    float2* Ah = (float2*)(ws + AH_OFF);
    int tid = threadIdx.x;
    {
        const float4* s4 = (const float4*)(ws + W2B_OFF);
        float4* d4 = (float4*)W2L;
        for (int u = tid; u < 3072; u += 256) d4[u] = s4[u];
        if (tid < 64) w1L[tid] = ((const float4*)(ws + W1F4_OFF))[tid];
    }
    __syncthreads();
    int wave = tid >> 6, lane = tid & 63;
    int cl = lane & 15, q = lane >> 4;
    int g = blockIdx.x * 4 + wave;
    int pix0 = g * 4;

    union AB { short8 v; unsigned short u[8]; };
    // ---- phase 1: h1 for sample m = cl, build A-frags (hi/lo bf16) ----
    int pb = pix0 + (cl >> 2), bb = cl & 3;
    float2 q0 = Xs[(bb*3+0)*NPIX + pb];
    float2 q1 = Xs[(bb*3+1)*NPIX + pb];
    float2 q2 = Xs[(bb*3+2)*NPIX + pb];
    float mg0 = sqrtf(q0.x*q0.x + q0.y*q0.y);
    float mg1 = sqrtf(q1.x*q1.x + q1.y*q1.y);
    float mg2 = sqrtf(q2.x*q2.x + q2.y*q2.y);
    AB ah[2], al[2];
#pragma unroll
    for (int kc = 0; kc < 2; kc++)
#pragma unroll
        for (int j = 0; j < 8; j++) {
            int k = kc*32 + q*8 + j;
            float4 wf = w1L[k];
            float hv = fmaxf(wf.w + wf.x*mg0 + wf.y*mg1 + wf.z*mg2, 0.f);
            unsigned ub = __builtin_bit_cast(unsigned, hv);
            ah[kc].u[j] = (unsigned short)(ub >> 16);
            float vh = __builtin_bit_cast(float, ub & 0xFFFF0000u);
            al[kc].u[j] = (unsigned short)(__builtin_bit_cast(unsigned, hv - vh) >> 16);
        }
    // ---- pixel geometry (lane-uniform in cl) ----
    int pixE = pix0 + q;
    int hh = pixE / 192, ww = pixE - hh*192;
    float yy = -1.0f + (float)hh * (2.0f/191.0f);
    float xx = -1.0f + (float)ww * (2.0f/191.0f);
    float rr = sqrtf(xx*xx + yy*yy + 1e-6f);
    float lr = __logf(rr);
    float phi = atan2f(yy, xx);
    // ---- streaming loop over 12 channel tiles ----
    float sm0 = 0.f, sm1 = 0.f, sm2 = 0.f, sm3 = 0.f;
    float Wr[4][3];
#pragma unroll
    for (int r = 0; r < 4; r++) { Wr[r][0] = 0.f; Wr[r][1] = 0.f; Wr[r][2] = 0.f; }
#pragma unroll 2
    for (int t = 0; t < 12; t++) {
        floatx4 a = {0.f, 0.f, 0.f, 0.f};
#pragma unroll
        for (int kc = 0; kc < 2; kc++) {
            int ob = (((kc*12 + t)*2)*64 + lane)*16;
            short8 bh = *(const short8*)(W2L + ob);
            short8 bl = *(const short8*)(W2L + ob + 1024);
            a = __builtin_amdgcn_mfma_f32_16x16x32_bf16(ah[kc].v, bh, a, 0, 0, 0);
            a = __builtin_amdgcn_mfma_f32_16x16x32_bf16(al[kc].v, bh, a, 0, 0, 0);
            a = __builtin_amdgcn_mfma_f32_16x16x32_bf16(ah[kc].v, bl, a, 0, 0, 0);
        }
        int c = t*16 + cl;
        float sc_ = bnA[c], sh_ = bnA[192 + c];
        float e0 = __expf(a[0]*sc_ + sh_);
        float e1 = __expf(a[1]*sc_ + sh_);
        float e2 = __expf(a[2]*sc_ + sh_);
        float e3 = __expf(a[3]*sc_ + sh_);
        sm0 += e0; sm1 += e1; sm2 += e2; sm3 += e3;
        int sB = c >> 6, o = c & 63;
#pragma unroll
        for (int i = 0; i < 3; i++) {
            int pidx = (sB*3 + i)*64 + o;
            float4 pa = pcA4[pidx];
            float2 pbv = pcB2[pidx];
            float dl = lr - pa.y, dp = phi - pa.w;
            float gv = __expf(pa.x*dl*dl + pa.z*dp*dp + pbv.y) * __cosf(pbv.x*rr);
            Wr[0][i] += e0*gv; Wr[1][i] += e1*gv;
            Wr[2][i] += e2*gv; Wr[3][i] += e3*gv;
        }
    }
    // ---- softmax denominators across the 16 cl lanes ----
#pragma unroll
    for (int sh = 1; sh < 16; sh <<= 1) {
        sm0 += __shfl_xor(sm0, sh); sm1 += __shfl_xor(sm1, sh);
        sm2 += __shfl_xor(sm2, sh); sm3 += __shfl_xor(sm3, sh);
    }
    float inv0 = 1.0f/sm0, inv1 = 1.0f/sm1, inv2 = 1.0f/sm2, inv3 = 1.0f/sm3;
    // ---- A accumulation ----
    float are = 0.f, aim = 0.f;
#pragma unroll
    for (int i = 0; i < 3; i++) {
        float2 x0 = Xs[(0*3+i)*NPIX + pixE];
        float2 x1 = Xs[(1*3+i)*NPIX + pixE];
        float2 x2 = Xs[(2*3+i)*NPIX + pixE];
        float2 x3 = Xs[(3*3+i)*NPIX + pixE];
        float w0v = Wr[0][i]*inv0, w1v = Wr[1][i]*inv1;
        float w2v = Wr[2][i]*inv2, w3v = Wr[3][i]*inv3;
        are += w0v*x0.x + w1v*x1.x + w2v*x2.x + w3v*x3.x;
        aim += w0v*x0.y + w1v*x1.y + w2v*x2.y + w3v*x3.y;
    }
#pragma unroll
    for (int sh = 1; sh < 16; sh <<= 1) {
        are += __shfl_xor(are, sh);
        aim += __shfl_xor(aim, sh);
    }
    if (cl == 0) {
        int hs = hh + 96; if (hs >= 192) hs -= 192;
        int wsx = ww + 96; if (wsx >= 192) wsx -= 192;
        Ah[hs*192 + wsx] = make_float2(are, aim);
    }
}

// ---------------- K6a: interval-masked IDFT -> xf (split path) --------------
__global__ __launch_bounds__(192) void k_ifft(char* ws) {
    __shared__ float2 twsh[192];
    __shared__ float2 Ssh[3][96];
    __shared__ int iL[3], iH[3];
    const float2* tw = (const float2*)(ws + TW_OFF);
    const int* idx = (const int*)(ws + IDX_OFF);
    const float2* Ah = (const float2*)(ws + AH_OFF);
    float* xf = (float*)(ws + XF_OFF);
    int tid = threadIdx.x;
    int y = blockIdx.x;
    int o = blockIdx.y;
    int op = (o + 32) & 63;
    twsh[tid] = tw[tid];
    if (tid < 3) { iL[tid] = idx[(op*3 + tid)*2]; iH[tid] = idx[(op*3 + tid)*2 + 1]; }
    __syncthreads();
    int l0 = iL[0], u0 = iH[0], l1 = iL[1], u1 = iH[1], l2 = iL[2], u2 = iH[2];
    int n0 = u0 - l0, n1 = u1 - l1, n2 = u2 - l2;
    int p1 = n0 + n1, T = p1 + n2;
    float2 stepy = twsh[y];
    for (int t = tid; t < T; t += 192) {
        int i, off, lo, hi;
        if (t < n0)      { i = 0; off = t;      lo = l0; hi = u0; }
        else if (t < p1) { i = 1; off = t - n0; lo = l1; hi = u1; }
        else             { i = 2; off = t - p1; lo = l2; hi = u2; }
        int wq = lo + off;
        float2 e = twsh[(lo * y) % 192];
        float sx = 0.f, sy = 0.f;
        for (int hq = lo; hq < hi; hq++) {
            float2 a = Ah[hq*192 + wq];
            sx += a.x*e.x - a.y*e.y;
            sy += a.x*e.y + a.y*e.x;
            float ex = e.x*stepy.x - e.y*stepy.y;
            e.y = e.x*stepy.y + e.y*stepy.x;
            e.x = ex;
        }
        Ssh[i][off] = make_float2(sx, sy);
    }
    __syncthreads();
    int col = tid;
    float2 stepc = twsh[col];
    float accre = 0.f;
#pragma unroll
    for (int i = 0; i < 3; i++) {
        int lo = iL[i];
        int wi = iH[i] - lo;
        float2 e = twsh[(lo * col) % 192];
        for (int off = 0; off < wi; off++) {
            float2 S = Ssh[i][off];
            accre += S.x*e.x - S.y*e.y;
            float ex = e.x*stepc.x - e.y*stepc.y;
            e.y = e.x*stepc.y + e.y*stepc.x;
            e.x = ex;
        }
    }
    xf[o*NPIX + y*192 + col] = accre * (1.0f / 36864.0f);
}

// ---------------- K6b: 3x3 conv (sgpr weights) + mix (split path) -----------
__global__ __launch_bounds__(192) void k_conv(const float* x, const float* convw,
                                              const float* mixp, const float* xf,
                                              float* out) {
    int col = threadIdx.x;
    int y = blockIdx.x;
    int b = blockIdx.y;
    float xv[27];
#pragma unroll
    for (int i = 0; i < 3; i++)
#pragma unroll
        for (int dy = 0; dy < 3; dy++)
#pragma unroll
            for (int dx = 0; dx < 3; dx++) {
                int yq = y + dy - 1, xq = col + dx - 1;
                bool ok = (yq >= 0) & (yq < 192) & (xq >= 0) & (xq < 192);
                xv[(i*3 + dy)*3 + dx] = ok ? x[(b*3+i)*NPIX + yq*192 + xq] : 0.f;
            }
    float mixv = mixp[0];
    float onem = 1.0f - mixv;
    for (int o = 0; o < 64; o++) {
        float s = 0.f;
#pragma unroll
        for (int c = 0; c < 27; c++) s += xv[c] * convw[o*27 + c];
        float xfv = xf[o*NPIX + y*192 + col];
        out[((b*64 + o)*192 + y)*192 + col] = mixv*xfv + onem*s;
    }
}

// ---------------- K6 (fallback): fused IDFT + conv + mix --------------------
__global__ __launch_bounds__(192) void k_final(const float* x, const float* convw,
                                               const float* mixp, float* out, char* ws) {
    __shared__ float2 twsh[192];
    __shared__ float2 Ssh[3][96];
    __shared__ float cwsh[27];
    __shared__ int iL[3], iH[3];
    const float2* tw = (const float2*)(ws + TW_OFF);
    const int* idx = (const int*)(ws + IDX_OFF);
    const float2* Ah = (const float2*)(ws + AH_OFF);
    int tid = threadIdx.x;
    int y = blockIdx.x;
    int o = blockIdx.y;
    int op = (o + 32) & 63;
    twsh[tid] = tw[tid];
    if (tid < 27) cwsh[tid] = convw[o*27 + tid];
    if (tid < 3) { iL[tid] = idx[(op*3 + tid)*2]; iH[tid] = idx[(op*3 + tid)*2 + 1]; }
    __syncthreads();
    int l0 = iL[0], u0 = iH[0], l1 = iL[1], u1 = iH[1], l2 = iL[2], u2 = iH[2];
    int n0 = u0 - l0, n1 = u1 - l1, n2 = u2 - l2;
    int p1 = n0 + n1, T = p1 + n2;
    for (int t = tid; t < T; t += 192) {
        int i, off, lo, hi;
        if (t < n0)      { i = 0; off = t;      lo = l0; hi = u0; }
        else if (t < p1) { i = 1; off = t - n0; lo = l1; hi = u1; }
        else             { i = 2; off = t - p1; lo = l2; hi = u2; }
        int wq = lo + off;
        float sx = 0.f, sy = 0.f;
        int m = (lo * y) % 192;
        for (int hq = lo; hq < hi; hq++) {
            float2 a = Ah[hq*192 + wq];
            float2 e = twsh[m];
            sx += a.x*e.x - a.y*e.y;
            sy += a.x*e.y + a.y*e.x;
            m += y; if (m >= 192) m -= 192;
        }
        Ssh[i][off] = make_float2(sx, sy);
    }
    __syncthreads();
    int col = tid;
    float accre = 0.f;
#pragma unroll
    for (int i = 0; i < 3; i++) {
        int lo = iL[i];
        int wi = iH[i] - lo;
        int m = (lo * col) % 192;
        for (int off = 0; off < wi; off++) {
            float2 S = Ssh[i][off];
            float2 e = twsh[m];
            accre += S.x*e.x - S.y*e.y;
            m += col; if (m >= 192) m -= 192;
        }
    }
    float xfv = accre * (1.0f / 36864.0f);
    float mixv = mixp[0];
    float onem = 1.0f - mixv;
#pragma unroll
    for (int b = 0; b < 4; b++) {
        float s = 0.f;
#pragma unroll
        for (int i = 0; i < 3; i++) {
            const float* xp = x + (b*3 + i)*NPIX;
#pragma unroll
            for (int dy = -1; dy <= 1; dy++) {
                int yq = y + dy;
                if (yq < 0 || yq >= 192) continue;
                const float* rowp = xp + yq*192;
#pragma unroll
                for (int dx = -1; dx <= 1; dx++) {
                    int xq = col + dx;
                    if (xq < 0 || xq >= 192) continue;
                    s += rowp[xq] * cwsh[i*9 + (dy+1)*3 + (dx+1)];
                }
            }
        }
        out[((b*64 + o)*192 + y)*192 + col] = mixv*xfv + onem*s;
    }
}

extern "C" void kernel_launch(void* const* d_in, const int* in_sizes, int n_in,
                              void* d_out, int out_size, void* d_ws, size_t ws_size,
                              hipStream_t stream) {
    const float* x      = (const float*)d_in[0];
    const float* freq   = (const float*)d_in[1];
    const float* theta  = (const float*)d_in[2];
    const float* sigma  = (const float*)d_in[3];
    const float* f0     = (const float*)d_in[4];
    const float* theta0 = (const float*)d_in[5];
    const float* aw1    = (const float*)d_in[6];
    const float* ab1    = (const float*)d_in[7];
    const float* aw2    = (const float*)d_in[8];
    // d_in[9] = attn_b2: cancelled exactly by BN mean-subtraction, unused
    const float* bnw    = (const float*)d_in[10];
    const float* bnb    = (const float*)d_in[11];
    const float* mixp   = (const float*)d_in[12];
    const float* convw  = (const float*)d_in[13];
    const float* fbs    = (const float*)d_in[14];
    float* out = (float*)d_out;
    char* ws = (char*)d_ws;
    if (ws_size < (size_t)WS_FUSED) return;

    hipMemsetAsync(ws + M2_OFF, 0, 16640, stream);
    k_pre  <<<1, 256, 0, stream>>>(freq, theta, sigma, f0, theta0, fbs,
                                   aw1, ab1, aw2, ws);
    k_dft1 <<<dim3(12, 48),  192, 0, stream>>>(x, ws);
    k_dft2 <<<dim3(12, 192), 192, 0, stream>>>(ws);
    k_stats<<<288, 256, 0, stream>>>(aw1, ab1, ws);
    k_bn   <<<192, 64, 0, stream>>>(aw2, bnw, bnb, ws);
    k_attn <<<2304, 256, 0, stream>>>(ws);
    if (ws_size >= (size_t)WS_SPLIT) {
        k_ifft <<<dim3(192, 64), 192, 0, stream>>>(ws);
        k_conv <<<dim3(192, 4),  192, 0, stream>>>(x, convw, mixp,
                                                   (const float*)(ws + XF_OFF), out);
    } else {
        k_final<<<dim3(192, 64), 192, 0, stream>>>(x, convw, mixp, out, ws);
    }
}

// Round 4
// 368.935 us; speedup vs baseline: 1.8754x; 1.1777x over previous
//
#include <hip/hip_runtime.h>
#include <math.h>

// Problem constants
#define NPIX  36864            // 192*192
#define PI2   6.28318530717958647692f

// Workspace layout (bytes)
#define TW_OFF    0            // 192 float2 twiddles e^{+2pi i n/192}
#define PCA_OFF   1536         // 576 float4 {a1, lf0, a2, th}
#define PCB_OFF   10752        // 576 float2 {fr, lsc}
#define W1F4_OFF  15360        // 64 float4 {w1[0..2], b1}
#define W2B_OFF   16384        // MFMA B-frags bf16 hi/lo: [kc][t][h][lane][8] = 49152 B
#define BN_OFF    65536        // 192 scale + 192 shift
#define IDX_OFF   67072        // 192*2 ints shifted intervals [o][i]{lo,hi}
#define M2_OFF    68608        // 64*64 M2 + 64 m1 floats (zeroed)
#define T1_OFF    85248        // 12*36864 float2 stage-1 DFT
#define XS_OFF    3624192      // 12*36864 float2 shifted spectrum
#define AH_OFF    7163136      // 36864 float2 ifftshifted A_tot
#define XF_OFF    7458048      // 64*36864 float xf (split path only)
#define WS_FUSED  7458048
#define WS_SPLIT  16895232

typedef __attribute__((ext_vector_type(8))) short short8;
typedef __attribute__((ext_vector_type(4))) float floatx4;

// ---------------- K0: precompute twiddles, params, W2 MFMA frags, intervals -
__global__ void k_pre(const float* freq, const float* theta, const float* sigma,
                      const float* f0, const float* theta0, const float* fbs,
                      const float* w1, const float* b1v, const float* w2,
                      char* ws) {
    float2* tw   = (float2*)(ws + TW_OFF);
    float4* pcA  = (float4*)(ws + PCA_OFF);
    float2* pcB  = (float2*)(ws + PCB_OFF);
    float4* w1f4 = (float4*)(ws + W1F4_OFF);
    unsigned short* w2b = (unsigned short*)(ws + W2B_OFF);
    int* idx = (int*)(ws + IDX_OFF);
    int tid = threadIdx.x;
    for (int n = tid; n < 192; n += blockDim.x) {
        float th = PI2 * (float)n / 192.0f;
        tw[n] = make_float2(cosf(th), sinf(th));
    }
    for (int t = tid; t < 576; t += blockDim.x) {
        int s = t / 192, rem = t % 192, o = rem / 3, i = rem % 3;
        float fr = freq[t], th = theta[t], sg = sigma[t], f0v = f0[t], th0 = theta0[t];
        float lg  = logf(sg / f0v);
        float a1  = -1.0f / (2.0f * lg * lg);
        float lf0 = logf(f0v);
        float a2  = -1.0f / (2.0f * th0 * th0);
        float lsc = -logf(PI2 * sg * sg);          // log(1/(2pi sg^2))
        int pidx = (s*3 + i)*64 + o;
        pcA[pidx] = make_float4(a1, lf0, a2, th);
        pcB[pidx] = make_float2(fr, lsc);
    }
    for (int t = tid; t < 64; t += blockDim.x)
        w1f4[t] = make_float4(w1[t*3+0], w1[t*3+1], w1[t*3+2], b1v[t]);
    // W2 B-fragments: entry e = ((kc*12+t)*2+h)*64+lane holds 8 bf16 (j=0..7)
    for (int u = tid; u < 24576; u += blockDim.x) {
        int j = u & 7; int v = u >> 3;
        int l = v & 63; v >>= 6;
        int hsel = v & 1; v >>= 1;
        int t = v % 12; int kc = v / 12;
        int k = kc*32 + (l>>4)*8 + j;
        int c = t*16 + (l & 15);
        float wv = w2[c*64 + k];
        unsigned ub = __builtin_bit_cast(unsigned, wv);
        unsigned short hi = (unsigned short)(ub >> 16);
        float vh = __builtin_bit_cast(float, ub & 0xFFFF0000u);
        unsigned short lo = (unsigned short)(__builtin_bit_cast(unsigned, wv - vh) >> 16);
        w2b[u] = hsel ? lo : hi;
    }
    for (int t = tid; t < 192; t += blockDim.x) {
        int lo = (int)floorf((fbs[t*2+0] + 1.0f) * 0.5f * 192.0f) - 96;
        int hi = (int)floorf((fbs[t*2+1] + 1.0f) * 0.5f * 192.0f) - 96;
        lo = max(0, min(96, lo));
        hi = max(0, min(96, hi));
        if (hi < lo) hi = lo;
        idx[t*2+0] = lo; idx[t*2+1] = hi;
    }
}

// ---------------- K1: stage-1 forward DFT over h (x real), 8 rows/block -----
__global__ __launch_bounds__(192) void k_dft1(const float* x, char* ws) {
    __shared__ float2 twsh[192];
    const float2* tw = (const float2*)(ws + TW_OFF);
    float2* t1 = (float2*)(ws + T1_OFF);
    int tid = threadIdx.x;
    twsh[tid] = tw[tid];
    __syncthreads();
    int bi = blockIdx.x;
    int y0 = blockIdx.y * 8;      // 24 tiles of 8 rows
    int w  = tid;
    const float* xp = x + bi * NPIX;
    float2 acc[8];
#pragma unroll
    for (int d = 0; d < 8; d++) acc[d] = make_float2(0.f, 0.f);
    for (int h = 0; h < 192; h++) {
        float xv = xp[h*192 + w];
        int m = (h * y0) % 192;
#pragma unroll
        for (int d = 0; d < 8; d++) {
            float2 e = twsh[m];                    // e^{-i th} = (c, -s)
            acc[d].x += xv * e.x;
            acc[d].y -= xv * e.y;
            m += h; if (m >= 192) m -= 192;
        }
    }
    float2* op = t1 + bi * NPIX;
#pragma unroll
    for (int d = 0; d < 8; d++) op[(y0 + d)*192 + w] = acc[d];
}

// ---------------- K2: stage-2 forward DFT over w + full fftshift write ------
// Twiddle via register rotation (re-seeded every 32 steps) - no per-lane LDS.
__global__ __launch_bounds__(192) void k_dft2(char* ws) {
    __shared__ float2 twsh[192];
    __shared__ float2 row[192];
    const float2* tw = (const float2*)(ws + TW_OFF);
    const float2* t1 = (const float2*)(ws + T1_OFF);
    float2* Xs = (float2*)(ws + XS_OFF);
    int tid = threadIdx.x;
    int bi = blockIdx.x, y = blockIdx.y;
    twsh[tid] = tw[tid];
    row[tid]  = t1[bi*NPIX + y*192 + tid];
    __syncthreads();
    int kx = tid;
    float2 st = twsh[kx];
    float2 acc = make_float2(0.f, 0.f);
#pragma unroll 1
    for (int w0 = 0; w0 < 192; w0 += 32) {
        float2 e = twsh[(w0 * kx) % 192];
#pragma unroll
        for (int w = 0; w < 32; w++) {
            float2 t = row[w0 + w];
            acc.x += t.x*e.x + t.y*e.y;          // t * conj(e)
            acc.y += t.y*e.x - t.x*e.y;
            float ex = e.x*st.x - e.y*st.y;
            e.y = e.x*st.y + e.y*st.x;
            e.x = ex;
        }
    }
    int b = bi / 3, i = bi % 3;
    int bs = (b + 2) & 3;
    int is = (i + 1) % 3;
    int ys = y + 96;  if (ys >= 192) ys -= 192;
    int ks = kx + 96; if (ks >= 192) ks -= 192;
    Xs[(bs*3 + is)*NPIX + ys*192 + ks] = acc;
}

// ---------------- K3: MFMA SYRK for BN stats: M2 = H1^T H1, m1 = sum(H1) ----
// Tile = 64 samples. Frag content for A and B is IDENTICAL for C=H1^T*H1:
// lane l holds h1[k=(l>>4)*8+j][ch=l&15] -> one LDS slot serves both.
__global__ __launch_bounds__(256) void k_stats(char* ws) {
    __shared__ float magL[192];                    // [s][i] at s*3+i
    __shared__ float4 w1L[64];
    __shared__ float m1L[64];
    __shared__ __align__(16) unsigned short fragH[512*8];  // z*8, z=(kc*4+cb)*64+l
    __shared__ __align__(16) unsigned short fragL[512*8];
    const float2* Xs = (const float2*)(ws + XS_OFF);
    float* M2 = (float*)(ws + M2_OFF);
    int tid = threadIdx.x;
    int wave = tid >> 6, lane = tid & 63;
    if (tid < 64) { w1L[tid] = ((const float4*)(ws + W1F4_OFF))[tid]; m1L[tid] = 0.f; }
    __syncthreads();
    int cch = wave*16 + (lane & 15);               // this thread's channel
    float4 wf = w1L[cch];
    float msum = 0.f;
    floatx4 acc[4];
#pragma unroll
    for (int nb = 0; nb < 4; nb++) acc[nb] = (floatx4){0.f, 0.f, 0.f, 0.f};
    union AB { short8 v; unsigned short u[8]; };
#pragma unroll 1
    for (int it = 0; it < 4; it++) {
        int tile = blockIdx.x * 4 + it;            // 576*4 = 2304 tiles
        int S0 = tile * 64;
        int b = S0 / NPIX;                         // NPIX%64==0 -> const per tile
        int p0 = S0 - b*NPIX;
        // Phase A: coalesced mags
        if (tid < 192) {
            int i = tid >> 6, s = tid & 63;
            float2 v = Xs[(b*3 + i)*NPIX + p0 + s];
            magL[s*3 + i] = sqrtf(v.x*v.x + v.y*v.y);
        }
        __syncthreads();
        // Phase B: build fragment slots (kc=0,1), bf16 hi/lo
#pragma unroll
        for (int kc = 0; kc < 2; kc++) {
            AB h8, l8;
#pragma unroll
            for (int j = 0; j < 8; j++) {
                int s = kc*32 + (lane>>4)*8 + j;
                float mg0 = magL[s*3], mg1 = magL[s*3+1], mg2 = magL[s*3+2];
                float hv = fmaxf(wf.w + wf.x*mg0 + wf.y*mg1 + wf.z*mg2, 0.f);
                msum += hv;
                unsigned ub = __builtin_bit_cast(unsigned, hv);
                h8.u[j] = (unsigned short)(ub >> 16);
                float vh = __builtin_bit_cast(float, ub & 0xFFFF0000u);
                l8.u[j] = (unsigned short)(__builtin_bit_cast(unsigned, hv - vh) >> 16);
            }
            int z = (kc*4 + wave)*64 + lane;
            *(short8*)&fragH[z*8] = h8.v;
            *(short8*)&fragL[z*8] = l8.v;
        }
        __syncthreads();
        // MFMA: wave computes row-block `wave` of C
        short8 Ah0 = *(const short8*)&fragH[((0*4+wave)*64 + lane)*8];
        short8 Ah1 = *(const short8*)&fragH[((1*4+wave)*64 + lane)*8];
        short8 Al0 = *(const short8*)&fragL[((0*4+wave)*64 + lane)*8];
        short8 Al1 = *(const short8*)&fragL[((1*4+wave)*64 + lane)*8];
#pragma unroll
        for (int nb = 0; nb < 4; nb++) {
            short8 Bh0 = *(const short8*)&fragH[((0*4+nb)*64 + lane)*8];
            short8 Bh1 = *(const short8*)&fragH[((1*4+nb)*64 + lane)*8];
            short8 Bl0 = *(const short8*)&fragL[((0*4+nb)*64 + lane)*8];
            short8 Bl1 = *(const short8*)&fragL[((1*4+nb)*64 + lane)*8];
            floatx4 a = acc[nb];
            a = __builtin_amdgcn_mfma_f32_16x16x32_bf16(Ah0, Bh0, a, 0, 0, 0);
            a = __builtin_amdgcn_mfma_f32_16x16x32_bf16(Al0, Bh0, a, 0, 0, 0);
            a = __builtin_amdgcn_mfma_f32_16x16x32_bf16(Ah0, Bl0, a, 0, 0, 0);
            a = __builtin_amdgcn_mfma_f32_16x16x32_bf16(Ah1, Bh1, a, 0, 0, 0);
            a = __builtin_amdgcn_mfma_f32_16x16x32_bf16(Al1, Bh1, a, 0, 0, 0);
            a = __builtin_amdgcn_mfma_f32_16x16x32_bf16(Ah1, Bl1, a, 0, 0, 0);
            acc[nb] = a;
        }
        __syncthreads();                           // LDS reused next tile
    }
    // write C partials (C layout: col=lane&15, row=(lane>>4)*4+reg)
#pragma unroll
    for (int nb = 0; nb < 4; nb++)
#pragma unroll
        for (int r = 0; r < 4; r++) {
            int row = wave*16 + (lane>>4)*4 + r;
            int col = nb*16 + (lane & 15);
            atomicAdd(&M2[row*64 + col], acc[nb][r]);
        }
    atomicAdd(&m1L[cch], msum);
    __syncthreads();
    if (tid < 64) atomicAdd(&M2[4096 + tid], m1L[tid]);
}

// ---------------- K4: BN scale/shift, one block per channel -----------------
__global__ __launch_bounds__(64) void k_bn(const float* w2, const float* bnw,
                                           const float* bnb, char* ws) {
    const float* M2 = (const float*)(ws + M2_OFF);
    const float* m1 = M2 + 4096;
    float* bnsc = (float*)(ws + BN_OFF);
    float* bnsh = bnsc + 192;
    int c = blockIdx.x;
    int jj = threadIdx.x;
    const float* row = w2 + c*64;
    float rj = row[jj];
    float inner = 0.f;
    const float* m2r = M2 + jj*64;
    for (int k = 0; k < 64; k++) inner += row[k] * m2r[k];
    float qpart = rj * inner;
    float dpart = rj * m1[jj];
#pragma unroll
    for (int sh = 32; sh >= 1; sh >>= 1) {
        qpart += __shfl_xor(qpart, sh);
        dpart += __shfl_xor(dpart, sh);
    }
    if (jj == 0) {
        const float invN = 1.0f / 147456.0f;
        float d = dpart * invN;
        float qv = qpart * invN;
        float var = qv - d*d;
        float rstd = rsqrtf(var + 1e-5f);
        float scale = bnw[c] * rstd;
        bnsc[c] = scale;
        bnsh[c] = bnb[c] - d * scale;
    }
}

// ---------------- K5: MFMA attention + gabor -> A_tot (online softmax) ------
__global__ __launch_bounds__(256) void k_attn(char* ws) {
    __shared__ __align__(16) char W2L[49152];
    __shared__ float4 w1L[64];
    const float2* Xs = (const float2*)(ws + XS_OFF);
    const float4* pcA4 = (const float4*)(ws + PCA_OFF);
    const float2* pcB2 = (const float2*)(ws + PCB_OFF);
    const float* bnA = (const float*)(ws + BN_OFF);   // [0..192) scale, [192..384) shift
    float2* Ah = (float2*)(ws + AH_OFF);
    int tid = threadIdx.x;
    {
        const float4* s4 = (const float4*)(ws + W2B_OFF);
        float4* d4 = (float4*)W2L;
        for (int u = tid; u < 3072; u += 256) d4[u] = s4[u];
        if (tid < 64) w1L[tid] = ((const float4*)(ws + W1F4_OFF))[tid];
    }
    __syncthreads();
    int wave = tid >> 6, lane = tid & 63;
    int cl = lane & 15, q = lane >> 4;
    int g = blockIdx.x * 4 + wave;
    int pix0 = g * 4;

    union AB { short8 v; unsigned short u[8]; };
    // ---- phase 1: h1 for sample m = cl, build A-frags (hi/lo bf16) ----
    int pb = pix0 + (cl >> 2), bb = cl & 3;
    float2 q0 = Xs[(bb*3+0)*NPIX + pb];
    float2 q1 = Xs[(bb*3+1)*NPIX + pb];
    float2 q2 = Xs[(bb*3+2)*NPIX + pb];
    float mg0 = sqrtf(q0.x*q0.x + q0.y*q0.y);
    float mg1 = sqrtf(q1.x*q1.x + q1.y*q1.y);
    float mg2 = sqrtf(q2.x*q2.x + q2.y*q2.y);
    AB ah[2], al[2];
#pragma unroll
    for (int kc = 0; kc < 2; kc++)
#pragma unroll
        for (int j = 0; j < 8; j++) {
            int k = kc*32 + q*8 + j;
            float4 wf = w1L[k];
            float hv = fmaxf(wf.w + wf.x*mg0 + wf.y*mg1 + wf.z*mg2, 0.f);
            unsigned ub = __builtin_bit_cast(unsigned, hv);
            ah[kc].u[j] = (unsigned short)(ub >> 16);
            float vh = __builtin_bit_cast(float, ub & 0xFFFF0000u);
            al[kc].u[j] = (unsigned short)(__builtin_bit_cast(unsigned, hv - vh) >> 16);
        }
    // ---- pixel geometry (lane-uniform in cl) ----
    int pixE = pix0 + q;
    int hh = pixE / 192, ww = pixE - hh*192;
    float yy = -1.0f + (float)hh * (2.0f/191.0f);
    float xx = -1.0f + (float)ww * (2.0f/191.0f);
    float rr = sqrtf(xx*xx + yy*yy + 1e-6f);
    float lr = __logf(rr);
    float phi = atan2f(yy, xx);
    // ---- streaming loop over 12 channel tiles ----
    float sm0 = 0.f, sm1 = 0.f, sm2 = 0.f, sm3 = 0.f;
    float Wr[4][3];
#pragma unroll
    for (int r = 0; r < 4; r++) { Wr[r][0] = 0.f; Wr[r][1] = 0.f; Wr[r][2] = 0.f; }
#pragma unroll 2
    for (int t = 0; t < 12; t++) {
        floatx4 a = {0.f, 0.f, 0.f, 0.f};
#pragma unroll
        for (int kc = 0; kc < 2; kc++) {
            int ob = (((kc*12 + t)*2)*64 + lane)*16;
            short8 bh = *(const short8*)(W2L + ob);
            short8 bl = *(const short8*)(W2L + ob + 1024);
            a = __builtin_amdgcn_mfma_f32_16x16x32_bf16(ah[kc].v, bh, a, 0, 0, 0);
            a = __builtin_amdgcn_mfma_f32_16x16x32_bf16(al[kc].v, bh, a, 0, 0, 0);
            a = __builtin_amdgcn_mfma_f32_16x16x32_bf16(ah[kc].v, bl, a, 0, 0, 0);
        }
        int c = t*16 + cl;
        float sc_ = bnA[c], sh_ = bnA[192 + c];
        float e0 = __expf(a[0]*sc_ + sh_);
        float e1 = __expf(a[1]*sc_ + sh_);
        float e2 = __expf(a[2]*sc_ + sh_);
        float e3 = __expf(a[3]*sc_ + sh_);
        sm0 += e0; sm1 += e1; sm2 += e2; sm3 += e3;
        int sB = c >> 6, o = c & 63;
#pragma unroll
        for (int i = 0; i < 3; i++) {
            int pidx = (sB*3 + i)*64 + o;
            float4 pa = pcA4[pidx];
            float2 pbv = pcB2[pidx];
            float dl = lr - pa.y, dp = phi - pa.w;
            float gv = __expf(pa.x*dl*dl + pa.z*dp*dp + pbv.y) * __cosf(pbv.x*rr);
            Wr[0][i] += e0*gv; Wr[1][i] += e1*gv;
            Wr[2][i] += e2*gv; Wr[3][i] += e3*gv;
        }
    }
    // ---- softmax denominators across the 16 cl lanes ----
#pragma unroll
    for (int sh = 1; sh < 16; sh <<= 1) {
        sm0 += __shfl_xor(sm0, sh); sm1 += __shfl_xor(sm1, sh);
        sm2 += __shfl_xor(sm2, sh); sm3 += __shfl_xor(sm3, sh);
    }
    float inv0 = 1.0f/sm0, inv1 = 1.0f/sm1, inv2 = 1.0f/sm2, inv3 = 1.0f/sm3;
    // ---- A accumulation ----
    float are = 0.f, aim = 0.f;
#pragma unroll
    for (int i = 0; i < 3; i++) {
        float2 x0 = Xs[(0*3+i)*NPIX + pixE];
        float2 x1 = Xs[(1*3+i)*NPIX + pixE];
        float2 x2 = Xs[(2*3+i)*NPIX + pixE];
        float2 x3 = Xs[(3*3+i)*NPIX + pixE];
        float w0v = Wr[0][i]*inv0, w1v = Wr[1][i]*inv1;
        float w2v = Wr[2][i]*inv2, w3v = Wr[3][i]*inv3;
        are += w0v*x0.x + w1v*x1.x + w2v*x2.x + w3v*x3.x;
        aim += w0v*x0.y + w1v*x1.y + w2v*x2.y + w3v*x3.y;
    }
#pragma unroll
    for (int sh = 1; sh < 16; sh <<= 1) {
        are += __shfl_xor(are, sh);
        aim += __shfl_xor(aim, sh);
    }
    if (cl == 0) {
        int hs = hh + 96; if (hs >= 192) hs -= 192;
        int wsx = ww + 96; if (wsx >= 192) wsx -= 192;
        Ah[hs*192 + wsx] = make_float2(are, aim);
    }
}

// ---------------- K6a: interval-masked IDFT -> xf (split path) --------------
__global__ __launch_bounds__(192) void k_ifft(char* ws) {
    __shared__ float2 twsh[192];
    __shared__ float2 Ssh[3][96];
    __shared__ int iL[3], iH[3];
    const float2* tw = (const float2*)(ws + TW_OFF);
    const int* idx = (const int*)(ws + IDX_OFF);
    const float2* Ah = (const float2*)(ws + AH_OFF);
    float* xf = (float*)(ws + XF_OFF);
    int tid = threadIdx.x;
    int y = blockIdx.x;
    int o = blockIdx.y;
    int op = (o + 32) & 63;
    twsh[tid] = tw[tid];
    if (tid < 3) { iL[tid] = idx[(op*3 + tid)*2]; iH[tid] = idx[(op*3 + tid)*2 + 1]; }
    __syncthreads();
    int l0 = iL[0], u0 = iH[0], l1 = iL[1], u1 = iH[1], l2 = iL[2], u2 = iH[2];
    int n0 = u0 - l0, n1 = u1 - l1, n2 = u2 - l2;
    int p1 = n0 + n1, T = p1 + n2;
    float2 stepy = twsh[y];
    for (int t = tid; t < T; t += 192) {
        int i, off, lo, hi;
        if (t < n0)      { i = 0; off = t;      lo = l0; hi = u0; }
        else if (t < p1) { i = 1; off = t - n0; lo = l1; hi = u1; }
        else             { i = 2; off = t - p1; lo = l2; hi = u2; }
        int wq = lo + off;
        float2 e = twsh[(lo * y) % 192];
        float sx = 0.f, sy = 0.f;
        for (int hq = lo; hq < hi; hq++) {
            float2 a = Ah[hq*192 + wq];
            sx += a.x*e.x - a.y*e.y;
            sy += a.x*e.y + a.y*e.x;
            float ex = e.x*stepy.x - e.y*stepy.y;
            e.y = e.x*stepy.y + e.y*stepy.x;
            e.x = ex;
        }
        Ssh[i][off] = make_float2(sx, sy);
    }
    __syncthreads();
    int col = tid;
    float2 stepc = twsh[col];
    float accre = 0.f;
#pragma unroll
    for (int i = 0; i < 3; i++) {
        int lo = iL[i];
        int wi = iH[i] - lo;
        float2 e = twsh[(lo * col) % 192];
        for (int off = 0; off < wi; off++) {
            float2 S = Ssh[i][off];
            accre += S.x*e.x - S.y*e.y;
            float ex = e.x*stepc.x - e.y*stepc.y;
            e.y = e.x*stepc.y + e.y*stepc.x;
            e.x = ex;
        }
    }
    xf[o*NPIX + y*192 + col] = accre * (1.0f / 36864.0f);
}

// ---------------- K6b: 3x3 conv (sgpr weights) + mix (split path) -----------
__global__ __launch_bounds__(192) void k_conv(const float* x, const float* convw,
                                              const float* mixp, const float* xf,
                                              float* out) {
    int col = threadIdx.x;
    int y = blockIdx.x;
    int b = blockIdx.y;
    float xv[27];
#pragma unroll
    for (int i = 0; i < 3; i++)
#pragma unroll
        for (int dy = 0; dy < 3; dy++)
#pragma unroll
            for (int dx = 0; dx < 3; dx++) {
                int yq = y + dy - 1, xq = col + dx - 1;
                bool ok = (yq >= 0) & (yq < 192) & (xq >= 0) & (xq < 192);
                xv[(i*3 + dy)*3 + dx] = ok ? x[(b*3+i)*NPIX + yq*192 + xq] : 0.f;
            }
    float mixv = mixp[0];
    float onem = 1.0f - mixv;
    for (int o = 0; o < 64; o++) {
        float s = 0.f;
#pragma unroll
        for (int c = 0; c < 27; c++) s += xv[c] * convw[o*27 + c];
        float xfv = xf[o*NPIX + y*192 + col];
        out[((b*64 + o)*192 + y)*192 + col] = mixv*xfv + onem*s;
    }
}

// ---------------- K6 (fallback): fused IDFT + conv + mix --------------------
__global__ __launch_bounds__(192) void k_final(const float* x, const float* convw,
                                               const float* mixp, float* out, char* ws) {
    __shared__ float2 twsh[192];
    __shared__ float2 Ssh[3][96];
    __shared__ float cwsh[27];
    __shared__ int iL[3], iH[3];
    const float2* tw = (const float2*)(ws + TW_OFF);
    const int* idx = (const int*)(ws + IDX_OFF);
    const float2* Ah = (const float2*)(ws + AH_OFF);
    int tid = threadIdx.x;
    int y = blockIdx.x;
    int o = blockIdx.y;
    int op = (o + 32) & 63;
    twsh[tid] = tw[tid];
    if (tid < 27) cwsh[tid] = convw[o*27 + tid];
    if (tid < 3) { iL[tid] = idx[(op*3 + tid)*2]; iH[tid] = idx[(op*3 + tid)*2 + 1]; }
    __syncthreads();
    int l0 = iL[0], u0 = iH[0], l1 = iL[1], u1 = iH[1], l2 = iL[2], u2 = iH[2];
    int n0 = u0 - l0, n1 = u1 - l1, n2 = u2 - l2;
    int p1 = n0 + n1, T = p1 + n2;
    for (int t = tid; t < T; t += 192) {
        int i, off, lo, hi;
        if (t < n0)      { i = 0; off = t;      lo = l0; hi = u0; }
        else if (t < p1) { i = 1; off = t - n0; lo = l1; hi = u1; }
        else             { i = 2; off = t - p1; lo = l2; hi = u2; }
        int wq = lo + off;
        float sx = 0.f, sy = 0.f;
        int m = (lo * y) % 192;
        for (int hq = lo; hq < hi; hq++) {
            float2 a = Ah[hq*192 + wq];
            float2 e = twsh[m];
            sx += a.x*e.x - a.y*e.y;
            sy += a.x*e.y + a.y*e.x;
            m += y; if (m >= 192) m -= 192;
        }
        Ssh[i][off] = make_float2(sx, sy);
    }
    __syncthreads();
    int col = tid;
    float accre = 0.f;
#pragma unroll
    for (int i = 0; i < 3; i++) {
        int lo = iL[i];
        int wi = iH[i] - lo;
        int m = (lo * col) % 192;
        for (int off = 0; off < wi; off++) {
            float2 S = Ssh[i][off];
            float2 e = twsh[m];
            accre += S.x*e.x - S.y*e.y;
            m += col; if (m >= 192) m -= 192;
        }
    }
    float xfv = accre * (1.0f / 36864.0f);
    float mixv = mixp[0];
    float onem = 1.0f - mixv;
#pragma unroll
    for (int b = 0; b < 4; b++) {
        float s = 0.f;
#pragma unroll
        for (int i = 0; i < 3; i++) {
            const float* xp = x + (b*3 + i)*NPIX;
#pragma unroll
            for (int dy = -1; dy <= 1; dy++) {
                int yq = y + dy;
                if (yq < 0 || yq >= 192) continue;
                const float* rowp = xp + yq*192;
#pragma unroll
                for (int dx = -1; dx <= 1; dx++) {
                    int xq = col + dx;
                    if (xq < 0 || xq >= 192) continue;
                    s += rowp[xq] * cwsh[i*9 + (dy+1)*3 + (dx+1)];
                }
            }
        }
        out[((b*64 + o)*192 + y)*192 + col] = mixv*xfv + onem*s;
    }
}

extern "C" void kernel_launch(void* const* d_in, const int* in_sizes, int n_in,
                              void* d_out, int out_size, void* d_ws, size_t ws_size,
                              hipStream_t stream) {
    const float* x      = (const float*)d_in[0];
    const float* freq   = (const float*)d_in[1];
    const float* theta  = (const float*)d_in[2];
    const float* sigma  = (const float*)d_in[3];
    const float* f0     = (const float*)d_in[4];
    const float* theta0 = (const float*)d_in[5];
    const float* aw1    = (const float*)d_in[6];
    const float* ab1    = (const float*)d_in[7];
    const float* aw2    = (const float*)d_in[8];
    // d_in[9] = attn_b2: cancelled exactly by BN mean-subtraction, unused
    const float* bnw    = (const float*)d_in[10];
    const float* bnb    = (const float*)d_in[11];
    const float* mixp   = (const float*)d_in[12];
    const float* convw  = (const float*)d_in[13];
    const float* fbs    = (const float*)d_in[14];
    float* out = (float*)d_out;
    char* ws = (char*)d_ws;
    if (ws_size < (size_t)WS_FUSED) return;

    hipMemsetAsync(ws + M2_OFF, 0, 16640, stream);
    k_pre  <<<1, 256, 0, stream>>>(freq, theta, sigma, f0, theta0, fbs,
                                   aw1, ab1, aw2, ws);
    k_dft1 <<<dim3(12, 24),  192, 0, stream>>>(x, ws);
    k_dft2 <<<dim3(12, 192), 192, 0, stream>>>(ws);
    k_stats<<<576, 256, 0, stream>>>(ws);
    k_bn   <<<192, 64, 0, stream>>>(aw2, bnw, bnb, ws);
    k_attn <<<2304, 256, 0, stream>>>(ws);
    if (ws_size >= (size_t)WS_SPLIT) {
        k_ifft <<<dim3(192, 64), 192, 0, stream>>>(ws);
        k_conv <<<dim3(192, 4),  192, 0, stream>>>(x, convw, mixp,
                                                   (const float*)(ws + XF_OFF), out);
    } else {
        k_final<<<dim3(192, 64), 192, 0, stream>>>(x, convw, mixp, out, ws);
    }
}

// Round 5
// 339.898 us; speedup vs baseline: 2.0356x; 1.0854x over previous
//
#include <hip/hip_runtime.h>
#include <math.h>

// Problem constants
#define NPIX  36864            // 192*192
#define PI2   6.28318530717958647692f

// Workspace layout (bytes)
#define TW_OFF    0            // 192 float2 twiddles e^{+2pi i n/192}
#define PCA_OFF   1536         // 576 float4 {a1, lf0, a2, th}
#define PCB_OFF   10752        // 576 float2 {fr, lsc}
#define W1F4_OFF  15360        // 64 float4 {w1[0..2], b1}
#define W2B_OFF   16384        // MFMA B-frags bf16 hi/lo: [kc][t][h][lane][8] = 49152 B
#define BN_OFF    65536        // 192 scale + 192 shift
#define IDX_OFF   67072        // 192*2 ints shifted intervals [o][i]{lo,hi}
#define M2_OFF    68608        // 64*64 M2 + 64 m1 floats (zeroed)
#define T1_OFF    85248        // 12*36864 float2 stage-1 DFT (h-half 0)
#define XS_OFF    3624192      // 12*36864 float2 shifted spectrum
#define AH_OFF    7163136      // 36864 float2 ifftshifted A_tot
#define XF_OFF    7458048      // 64*36864 float xf; ALSO aliased as T1 h-half-1
#define WS_FUSED  7458048
#define WS_SPLIT  16895232

typedef __attribute__((ext_vector_type(8))) short short8;
typedef __attribute__((ext_vector_type(4))) float floatx4;

// ---------------- K0: precompute twiddles, params, W2 MFMA frags, intervals -
__global__ void k_pre(const float* freq, const float* theta, const float* sigma,
                      const float* f0, const float* theta0, const float* fbs,
                      const float* w1, const float* b1v, const float* w2,
                      char* ws) {
    float2* tw   = (float2*)(ws + TW_OFF);
    float4* pcA  = (float4*)(ws + PCA_OFF);
    float2* pcB  = (float2*)(ws + PCB_OFF);
    float4* w1f4 = (float4*)(ws + W1F4_OFF);
    unsigned short* w2b = (unsigned short*)(ws + W2B_OFF);
    int* idx = (int*)(ws + IDX_OFF);
    int tid = threadIdx.x;
    for (int n = tid; n < 192; n += blockDim.x) {
        float th = PI2 * (float)n / 192.0f;
        tw[n] = make_float2(cosf(th), sinf(th));
    }
    for (int t = tid; t < 576; t += blockDim.x) {
        int s = t / 192, rem = t % 192, o = rem / 3, i = rem % 3;
        float fr = freq[t], th = theta[t], sg = sigma[t], f0v = f0[t], th0 = theta0[t];
        float lg  = logf(sg / f0v);
        float a1  = -1.0f / (2.0f * lg * lg);
        float lf0 = logf(f0v);
        float a2  = -1.0f / (2.0f * th0 * th0);
        float lsc = -logf(PI2 * sg * sg);          // log(1/(2pi sg^2))
        int pidx = (s*3 + i)*64 + o;
        pcA[pidx] = make_float4(a1, lf0, a2, th);
        pcB[pidx] = make_float2(fr, lsc);
    }
    for (int t = tid; t < 64; t += blockDim.x)
        w1f4[t] = make_float4(w1[t*3+0], w1[t*3+1], w1[t*3+2], b1v[t]);
    // W2 B-fragments: entry e = ((kc*12+t)*2+h)*64+lane holds 8 bf16 (j=0..7)
    for (int u = tid; u < 24576; u += blockDim.x) {
        int j = u & 7; int v = u >> 3;
        int l = v & 63; v >>= 6;
        int hsel = v & 1; v >>= 1;
        int t = v % 12; int kc = v / 12;
        int k = kc*32 + (l>>4)*8 + j;
        int c = t*16 + (l & 15);
        float wv = w2[c*64 + k];
        unsigned ub = __builtin_bit_cast(unsigned, wv);
        unsigned short hi = (unsigned short)(ub >> 16);
        float vh = __builtin_bit_cast(float, ub & 0xFFFF0000u);
        unsigned short lo = (unsigned short)(__builtin_bit_cast(unsigned, wv - vh) >> 16);
        w2b[u] = hsel ? lo : hi;
    }
    for (int t = tid; t < 192; t += blockDim.x) {
        int lo = (int)floorf((fbs[t*2+0] + 1.0f) * 0.5f * 192.0f) - 96;
        int hi = (int)floorf((fbs[t*2+1] + 1.0f) * 0.5f * 192.0f) - 96;
        lo = max(0, min(96, lo));
        hi = max(0, min(96, hi));
        if (hi < lo) hi = lo;
        idx[t*2+0] = lo; idx[t*2+1] = hi;
    }
}

// ---------------- K1s: stage-1 DFT over h, split into 2 h-halves ------------
// z=0 -> T1_OFF, z=1 -> XF_OFF (aliased; consumed by k_dft2 before k_ifft
// writes xf there). 1152 blocks for occupancy.
__global__ __launch_bounds__(192) void k_dft1s(const float* x, char* ws) {
    __shared__ float2 twsh[192];
    const float2* tw = (const float2*)(ws + TW_OFF);
    int tid = threadIdx.x;
    twsh[tid] = tw[tid];
    __syncthreads();
    int bi = blockIdx.x;
    int y0 = blockIdx.y * 4;
    int z  = blockIdx.z;
    float2* t1 = (float2*)(ws + (z ? XF_OFF : T1_OFF));
    int w  = tid;
    const float* xp = x + bi * NPIX;
    float2 acc[4];
#pragma unroll
    for (int d = 0; d < 4; d++) acc[d] = make_float2(0.f, 0.f);
    int h0 = z * 96;
    for (int h = h0; h < h0 + 96; h++) {
        float xv = xp[h*192 + w];
        int m = (h * y0) % 192;
#pragma unroll
        for (int d = 0; d < 4; d++) {
            float2 e = twsh[m];                    // e^{-i th} = (c, -s)
            acc[d].x += xv * e.x;
            acc[d].y -= xv * e.y;
            m += h; if (m >= 192) m -= 192;
        }
    }
    float2* op = t1 + bi * NPIX;
#pragma unroll
    for (int d = 0; d < 4; d++) op[(y0 + d)*192 + w] = acc[d];
}

// ---------------- K1 (fallback, fused path): full-h stage-1 DFT -------------
__global__ __launch_bounds__(192) void k_dft1(const float* x, char* ws) {
    __shared__ float2 twsh[192];
    const float2* tw = (const float2*)(ws + TW_OFF);
    float2* t1 = (float2*)(ws + T1_OFF);
    int tid = threadIdx.x;
    twsh[tid] = tw[tid];
    __syncthreads();
    int bi = blockIdx.x;
    int y0 = blockIdx.y * 4;
    int w  = tid;
    const float* xp = x + bi * NPIX;
    float2 acc[4];
#pragma unroll
    for (int d = 0; d < 4; d++) acc[d] = make_float2(0.f, 0.f);
    for (int h = 0; h < 192; h++) {
        float xv = xp[h*192 + w];
        int m = (h * y0) % 192;
#pragma unroll
        for (int d = 0; d < 4; d++) {
            float2 e = twsh[m];
            acc[d].x += xv * e.x;
            acc[d].y -= xv * e.y;
            m += h; if (m >= 192) m -= 192;
        }
    }
    float2* op = t1 + bi * NPIX;
#pragma unroll
    for (int d = 0; d < 4; d++) op[(y0 + d)*192 + w] = acc[d];
}

// ---------------- K2: stage-2 forward DFT over w + full fftshift write ------
__global__ __launch_bounds__(192) void k_dft2(char* ws, int split) {
    __shared__ float2 twsh[192];
    __shared__ float2 row[192];
    const float2* tw = (const float2*)(ws + TW_OFF);
    const float2* t1a = (const float2*)(ws + T1_OFF);
    const float2* t1b = (const float2*)(ws + XF_OFF);
    float2* Xs = (float2*)(ws + XS_OFF);
    int tid = threadIdx.x;
    int bi = blockIdx.x, y = blockIdx.y;
    twsh[tid] = tw[tid];
    {
        float2 v = t1a[bi*NPIX + y*192 + tid];
        if (split) {
            float2 v2 = t1b[bi*NPIX + y*192 + tid];
            v.x += v2.x; v.y += v2.y;
        }
        row[tid] = v;
    }
    __syncthreads();
    int kx = tid;
    float2 st = twsh[kx];
    float2 acc = make_float2(0.f, 0.f);
#pragma unroll 1
    for (int w0 = 0; w0 < 192; w0 += 32) {
        float2 e = twsh[(w0 * kx) % 192];
#pragma unroll
        for (int w = 0; w < 32; w++) {
            float2 t = row[w0 + w];
            acc.x += t.x*e.x + t.y*e.y;          // t * conj(e)
            acc.y += t.y*e.x - t.x*e.y;
            float ex = e.x*st.x - e.y*st.y;
            e.y = e.x*st.y + e.y*st.x;
            e.x = ex;
        }
    }
    int b = bi / 3, i = bi % 3;
    int bs = (b + 2) & 3;
    int is = (i + 1) % 3;
    int ys = y + 96;  if (ys >= 192) ys -= 192;
    int ks = kx + 96; if (ks >= 192) ks -= 192;
    Xs[(bs*3 + is)*NPIX + ys*192 + ks] = acc;
}

// ---------------- K3: MFMA SYRK for BN stats: M2 = H1^T H1, m1 = sum(H1) ----
__global__ __launch_bounds__(256) void k_stats(char* ws) {
    __shared__ float magL[192];                    // [s][i] at s*3+i
    __shared__ float4 w1L[64];
    __shared__ float m1L[64];
    __shared__ __align__(16) unsigned short fragH[512*8];  // z*8, z=(kc*4+cb)*64+l
    __shared__ __align__(16) unsigned short fragL[512*8];
    const float2* Xs = (const float2*)(ws + XS_OFF);
    float* M2 = (float*)(ws + M2_OFF);
    int tid = threadIdx.x;
    int wave = tid >> 6, lane = tid & 63;
    if (tid < 64) { w1L[tid] = ((const float4*)(ws + W1F4_OFF))[tid]; m1L[tid] = 0.f; }
    __syncthreads();
    int cch = wave*16 + (lane & 15);               // this thread's channel
    float4 wf = w1L[cch];
    float msum = 0.f;
    floatx4 acc[4];
#pragma unroll
    for (int nb = 0; nb < 4; nb++) acc[nb] = (floatx4){0.f, 0.f, 0.f, 0.f};
    union AB { short8 v; unsigned short u[8]; };
#pragma unroll 1
    for (int it = 0; it < 4; it++) {
        int tile = blockIdx.x * 4 + it;            // 576*4 = 2304 tiles
        int S0 = tile * 64;
        int b = S0 / NPIX;                         // NPIX%64==0 -> const per tile
        int p0 = S0 - b*NPIX;
        if (tid < 192) {
            int i = tid >> 6, s = tid & 63;
            float2 v = Xs[(b*3 + i)*NPIX + p0 + s];
            magL[s*3 + i] = sqrtf(v.x*v.x + v.y*v.y);
        }
        __syncthreads();
#pragma unroll
        for (int kc = 0; kc < 2; kc++) {
            AB h8, l8;
#pragma unroll
            for (int j = 0; j < 8; j++) {
                int s = kc*32 + (lane>>4)*8 + j;
                float mg0 = magL[s*3], mg1 = magL[s*3+1], mg2 = magL[s*3+2];
                float hv = fmaxf(wf.w + wf.x*mg0 + wf.y*mg1 + wf.z*mg2, 0.f);
                msum += hv;
                unsigned ub = __builtin_bit_cast(unsigned, hv);
                h8.u[j] = (unsigned short)(ub >> 16);
                float vh = __builtin_bit_cast(float, ub & 0xFFFF0000u);
                l8.u[j] = (unsigned short)(__builtin_bit_cast(unsigned, hv - vh) >> 16);
            }
            int z = (kc*4 + wave)*64 + lane;
            *(short8*)&fragH[z*8] = h8.v;
            *(short8*)&fragL[z*8] = l8.v;
        }
        __syncthreads();
        short8 Ah0 = *(const short8*)&fragH[((0*4+wave)*64 + lane)*8];
        short8 Ah1 = *(const short8*)&fragH[((1*4+wave)*64 + lane)*8];
        short8 Al0 = *(const short8*)&fragL[((0*4+wave)*64 + lane)*8];
        short8 Al1 = *(const short8*)&fragL[((1*4+wave)*64 + lane)*8];
#pragma unroll
        for (int nb = 0; nb < 4; nb++) {
            short8 Bh0 = *(const short8*)&fragH[((0*4+nb)*64 + lane)*8];
            short8 Bh1 = *(const short8*)&fragH[((1*4+nb)*64 + lane)*8];
            short8 Bl0 = *(const short8*)&fragL[((0*4+nb)*64 + lane)*8];
            short8 Bl1 = *(const short8*)&fragL[((1*4+nb)*64 + lane)*8];
            floatx4 a = acc[nb];
            a = __builtin_amdgcn_mfma_f32_16x16x32_bf16(Ah0, Bh0, a, 0, 0, 0);
            a = __builtin_amdgcn_mfma_f32_16x16x32_bf16(Al0, Bh0, a, 0, 0, 0);
            a = __builtin_amdgcn_mfma_f32_16x16x32_bf16(Ah0, Bl0, a, 0, 0, 0);
            a = __builtin_amdgcn_mfma_f32_16x16x32_bf16(Ah1, Bh1, a, 0, 0, 0);
            a = __builtin_amdgcn_mfma_f32_16x16x32_bf16(Al1, Bh1, a, 0, 0, 0);
            a = __builtin_amdgcn_mfma_f32_16x16x32_bf16(Ah1, Bl1, a, 0, 0, 0);
            acc[nb] = a;
        }
        __syncthreads();
    }
#pragma unroll
    for (int nb = 0; nb < 4; nb++)
#pragma unroll
        for (int r = 0; r < 4; r++) {
            int row = wave*16 + (lane>>4)*4 + r;
            int col = nb*16 + (lane & 15);
            atomicAdd(&M2[row*64 + col], acc[nb][r]);
        }
    atomicAdd(&m1L[cch], msum);
    __syncthreads();
    if (tid < 64) atomicAdd(&M2[4096 + tid], m1L[tid]);
}

// ---------------- K4: BN scale/shift, one block per channel -----------------
__global__ __launch_bounds__(64) void k_bn(const float* w2, const float* bnw,
                                           const float* bnb, char* ws) {
    const float* M2 = (const float*)(ws + M2_OFF);
    const float* m1 = M2 + 4096;
    float* bnsc = (float*)(ws + BN_OFF);
    float* bnsh = bnsc + 192;
    int c = blockIdx.x;
    int jj = threadIdx.x;
    const float* row = w2 + c*64;
    float rj = row[jj];
    float inner = 0.f;
    const float* m2r = M2 + jj*64;
    for (int k = 0; k < 64; k++) inner += row[k] * m2r[k];
    float qpart = rj * inner;
    float dpart = rj * m1[jj];
#pragma unroll
    for (int sh = 32; sh >= 1; sh >>= 1) {
        qpart += __shfl_xor(qpart, sh);
        dpart += __shfl_xor(dpart, sh);
    }
    if (jj == 0) {
        const float invN = 1.0f / 147456.0f;
        float d = dpart * invN;
        float qv = qpart * invN;
        float var = qv - d*d;
        float rstd = rsqrtf(var + 1e-5f);
        float scale = bnw[c] * rstd;
        bnsc[c] = scale;
        bnsh[c] = bnb[c] - d * scale;
    }
}

// ---------------- K5: MFMA attention + gabor -> A_tot (online softmax) ------
__global__ __launch_bounds__(256) void k_attn(char* ws) {
    __shared__ __align__(16) char W2L[49152];
    __shared__ float4 w1L[64];
    const float2* Xs = (const float2*)(ws + XS_OFF);
    const float4* pcA4 = (const float4*)(ws + PCA_OFF);
    const float2* pcB2 = (const float2*)(ws + PCB_OFF);
    const float* bnA = (const float*)(ws + BN_OFF);   // [0..192) scale, [192..384) shift
    float2* Ah = (float2*)(ws + AH_OFF);
    int tid = threadIdx.x;
    {
        const float4* s4 = (const float4*)(ws + W2B_OFF);
        float4* d4 = (float4*)W2L;
        for (int u = tid; u < 3072; u += 256) d4[u] = s4[u];
        if (tid < 64) w1L[tid] = ((const float4*)(ws + W1F4_OFF))[tid];
    }
    __syncthreads();
    int wave = tid >> 6, lane = tid & 63;
    int cl = lane & 15, q = lane >> 4;
    int g = blockIdx.x * 4 + wave;
    int pix0 = g * 4;

    union AB { short8 v; unsigned short u[8]; };
    int pb = pix0 + (cl >> 2), bb = cl & 3;
    float2 q0 = Xs[(bb*3+0)*NPIX + pb];
    float2 q1 = Xs[(bb*3+1)*NPIX + pb];
    float2 q2 = Xs[(bb*3+2)*NPIX + pb];
    float mg0 = sqrtf(q0.x*q0.x + q0.y*q0.y);
    float mg1 = sqrtf(q1.x*q1.x + q1.y*q1.y);
    float mg2 = sqrtf(q2.x*q2.x + q2.y*q2.y);
    AB ah[2], al[2];
#pragma unroll
    for (int kc = 0; kc < 2; kc++)
#pragma unroll
        for (int j = 0; j < 8; j++) {
            int k = kc*32 + q*8 + j;
            float4 wf = w1L[k];
            float hv = fmaxf(wf.w + wf.x*mg0 + wf.y*mg1 + wf.z*mg2, 0.f);
            unsigned ub = __builtin_bit_cast(unsigned, hv);
            ah[kc].u[j] = (unsigned short)(ub >> 16);
            float vh = __builtin_bit_cast(float, ub & 0xFFFF0000u);
            al[kc].u[j] = (unsigned short)(__builtin_bit_cast(unsigned, hv - vh) >> 16);
        }
    int pixE = pix0 + q;
    int hh = pixE / 192, ww = pixE - hh*192;
    float yy = -1.0f + (float)hh * (2.0f/191.0f);
    float xx = -1.0f + (float)ww * (2.0f/191.0f);
    float rr = sqrtf(xx*xx + yy*yy + 1e-6f);
    float lr = __logf(rr);
    float phi = atan2f(yy, xx);
    float sm0 = 0.f, sm1 = 0.f, sm2 = 0.f, sm3 = 0.f;
    float Wr[4][3];
#pragma unroll
    for (int r = 0; r < 4; r++) { Wr[r][0] = 0.f; Wr[r][1] = 0.f; Wr[r][2] = 0.f; }
#pragma unroll 2
    for (int t = 0; t < 12; t++) {
        floatx4 a = {0.f, 0.f, 0.f, 0.f};
#pragma unroll
        for (int kc = 0; kc < 2; kc++) {
            int ob = (((kc*12 + t)*2)*64 + lane)*16;
            short8 bh = *(const short8*)(W2L + ob);
            short8 bl = *(const short8*)(W2L + ob + 1024);
            a = __builtin_amdgcn_mfma_f32_16x16x32_bf16(ah[kc].v, bh, a, 0, 0, 0);
            a = __builtin_amdgcn_mfma_f32_16x16x32_bf16(al[kc].v, bh, a, 0, 0, 0);
            a = __builtin_amdgcn_mfma_f32_16x16x32_bf16(ah[kc].v, bl, a, 0, 0, 0);
        }
        int c = t*16 + cl;
        float sc_ = bnA[c], sh_ = bnA[192 + c];
        float e0 = __expf(a[0]*sc_ + sh_);
        float e1 = __expf(a[1]*sc_ + sh_);
        float e2 = __expf(a[2]*sc_ + sh_);
        float e3 = __expf(a[3]*sc_ + sh_);
        sm0 += e0; sm1 += e1; sm2 += e2; sm3 += e3;
        int sB = c >> 6, o = c & 63;
#pragma unroll
        for (int i = 0; i < 3; i++) {
            int pidx = (sB*3 + i)*64 + o;
            float4 pa = pcA4[pidx];
            float2 pbv = pcB2[pidx];
            float dl = lr - pa.y, dp = phi - pa.w;
            float gv = __expf(pa.x*dl*dl + pa.z*dp*dp + pbv.y) * __cosf(pbv.x*rr);
            Wr[0][i] += e0*gv; Wr[1][i] += e1*gv;
            Wr[2][i] += e2*gv; Wr[3][i] += e3*gv;
        }
    }
#pragma unroll
    for (int sh = 1; sh < 16; sh <<= 1) {
        sm0 += __shfl_xor(sm0, sh); sm1 += __shfl_xor(sm1, sh);
        sm2 += __shfl_xor(sm2, sh); sm3 += __shfl_xor(sm3, sh);
    }
    float inv0 = 1.0f/sm0, inv1 = 1.0f/sm1, inv2 = 1.0f/sm2, inv3 = 1.0f/sm3;
    float are = 0.f, aim = 0.f;
#pragma unroll
    for (int i = 0; i < 3; i++) {
        float2 x0 = Xs[(0*3+i)*NPIX + pixE];
        float2 x1 = Xs[(1*3+i)*NPIX + pixE];
        float2 x2 = Xs[(2*3+i)*NPIX + pixE];
        float2 x3 = Xs[(3*3+i)*NPIX + pixE];
        float w0v = Wr[0][i]*inv0, w1v = Wr[1][i]*inv1;
        float w2v = Wr[2][i]*inv2, w3v = Wr[3][i]*inv3;
        are += w0v*x0.x + w1v*x1.x + w2v*x2.x + w3v*x3.x;
        aim += w0v*x0.y + w1v*x1.y + w2v*x2.y + w3v*x3.y;
    }
#pragma unroll
    for (int sh = 1; sh < 16; sh <<= 1) {
        are += __shfl_xor(are, sh);
        aim += __shfl_xor(aim, sh);
    }
    if (cl == 0) {
        int hs = hh + 96; if (hs >= 192) hs -= 192;
        int wsx = ww + 96; if (wsx >= 192) wsx -= 192;
        Ah[hs*192 + wsx] = make_float2(are, aim);
    }
}

// ---------------- K6a: interval-masked IDFT -> xf, 8 rows per block ---------
// Phase B twiddles are y-independent: one rotation chain feeds 8 accumulators.
__global__ __launch_bounds__(192) void k_ifft(char* ws) {
    __shared__ float2 twsh[192];
    __shared__ float2 Ssh[8][3][97];               // +1 pad: stagger yy stride
    __shared__ int iL[3], iH[3];
    const float2* tw = (const float2*)(ws + TW_OFF);
    const int* idx = (const int*)(ws + IDX_OFF);
    const float2* Ah = (const float2*)(ws + AH_OFF);
    float* xf = (float*)(ws + XF_OFF);
    int tid = threadIdx.x;
    int y0 = blockIdx.x * 8;
    int o = blockIdx.y;
    int op = (o + 32) & 63;
    twsh[tid] = tw[tid];
    if (tid < 3) { iL[tid] = idx[(op*3 + tid)*2]; iH[tid] = idx[(op*3 + tid)*2 + 1]; }
    __syncthreads();
    int n0 = iH[0]-iL[0], n1 = iH[1]-iL[1], n2 = iH[2]-iL[2];
    int p1 = n0 + n1, T = p1 + n2;
    // Phase A: tgt = (task, y-pair); each handles 2 consecutive y
    for (int tgt = tid; tgt < 4*T; tgt += 192) {
        int task = tgt >> 2, yp = tgt & 3;
        int i, off, lo, hi;
        if (task < n0)      { i = 0; off = task;      lo = iL[0]; hi = iH[0]; }
        else if (task < p1) { i = 1; off = task - n0; lo = iL[1]; hi = iH[1]; }
        else                { i = 2; off = task - p1; lo = iL[2]; hi = iH[2]; }
        int wq = lo + off;
        int ya = y0 + yp*2, yb = ya + 1;
        float2 ea = twsh[(lo * ya) % 192], sta = twsh[ya];
        float2 eb = twsh[(lo * yb) % 192], stb = twsh[yb];
        float2 Sa = make_float2(0.f, 0.f), Sb = make_float2(0.f, 0.f);
        for (int hq = lo; hq < hi; hq++) {
            float2 a = Ah[hq*192 + wq];
            Sa.x += a.x*ea.x - a.y*ea.y;
            Sa.y += a.x*ea.y + a.y*ea.x;
            float ex = ea.x*sta.x - ea.y*sta.y;
            ea.y = ea.x*sta.y + ea.y*sta.x; ea.x = ex;
            Sb.x += a.x*eb.x - a.y*eb.y;
            Sb.y += a.x*eb.y + a.y*eb.x;
            ex = eb.x*stb.x - eb.y*stb.y;
            eb.y = eb.x*stb.y + eb.y*stb.x; eb.x = ex;
        }
        Ssh[yp*2  ][i][off] = Sa;
        Ssh[yp*2+1][i][off] = Sb;
    }
    __syncthreads();
    // Phase B: col = tid; one twiddle chain, 8 y-accumulators
    int col = tid;
    float2 stepc = twsh[col];
    float acc[8];
#pragma unroll
    for (int yy = 0; yy < 8; yy++) acc[yy] = 0.f;
#pragma unroll
    for (int i = 0; i < 3; i++) {
        int lo = iL[i];
        int wi = iH[i] - lo;
        float2 e = twsh[(lo * col) % 192];
        for (int off = 0; off < wi; off++) {
#pragma unroll
            for (int yy = 0; yy < 8; yy++) {
                float2 S = Ssh[yy][i][off];
                acc[yy] += S.x*e.x - S.y*e.y;
            }
            float ex = e.x*stepc.x - e.y*stepc.y;
            e.y = e.x*stepc.y + e.y*stepc.x;
            e.x = ex;
        }
    }
#pragma unroll
    for (int yy = 0; yy < 8; yy++)
        xf[o*NPIX + (y0 + yy)*192 + col] = acc[yy] * (1.0f / 36864.0f);
}

// ---------------- K6b: 3x3 conv (sgpr weights) + mix (split path) -----------
__global__ __launch_bounds__(192) void k_conv(const float* x, const float* convw,
                                              const float* mixp, const float* xf,
                                              float* out) {
    int col = threadIdx.x;
    int y = blockIdx.x;
    int b = blockIdx.y;
    float xv[27];
#pragma unroll
    for (int i = 0; i < 3; i++)
#pragma unroll
        for (int dy = 0; dy < 3; dy++)
#pragma unroll
            for (int dx = 0; dx < 3; dx++) {
                int yq = y + dy - 1, xq = col + dx - 1;
                bool ok = (yq >= 0) & (yq < 192) & (xq >= 0) & (xq < 192);
                xv[(i*3 + dy)*3 + dx] = ok ? x[(b*3+i)*NPIX + yq*192 + xq] : 0.f;
            }
    float mixv = mixp[0];
    float onem = 1.0f - mixv;
    for (int o = 0; o < 64; o++) {
        float s = 0.f;
#pragma unroll
        for (int c = 0; c < 27; c++) s += xv[c] * convw[o*27 + c];
        float xfv = xf[o*NPIX + y*192 + col];
        out[((b*64 + o)*192 + y)*192 + col] = mixv*xfv + onem*s;
    }
}

// ---------------- K6 (fallback): fused IDFT + conv + mix --------------------
__global__ __launch_bounds__(192) void k_final(const float* x, const float* convw,
                                               const float* mixp, float* out, char* ws) {
    __shared__ float2 twsh[192];
    __shared__ float2 Ssh[3][96];
    __shared__ float cwsh[27];
    __shared__ int iL[3], iH[3];
    const float2* tw = (const float2*)(ws + TW_OFF);
    const int* idx = (const int*)(ws + IDX_OFF);
    const float2* Ah = (const float2*)(ws + AH_OFF);
    int tid = threadIdx.x;
    int y = blockIdx.x;
    int o = blockIdx.y;
    int op = (o + 32) & 63;
    twsh[tid] = tw[tid];
    if (tid < 27) cwsh[tid] = convw[o*27 + tid];
    if (tid < 3) { iL[tid] = idx[(op*3 + tid)*2]; iH[tid] = idx[(op*3 + tid)*2 + 1]; }
    __syncthreads();
    int l0 = iL[0], u0 = iH[0], l1 = iL[1], u1 = iH[1], l2 = iL[2], u2 = iH[2];
    int n0 = u0 - l0, n1 = u1 - l1, n2 = u2 - l2;
    int p1 = n0 + n1, T = p1 + n2;
    for (int t = tid; t < T; t += 192) {
        int i, off, lo, hi;
        if (t < n0)      { i = 0; off = t;      lo = l0; hi = u0; }
        else if (t < p1) { i = 1; off = t - n0; lo = l1; hi = u1; }
        else             { i = 2; off = t - p1; lo = l2; hi = u2; }
        int wq = lo + off;
        float sx = 0.f, sy = 0.f;
        int m = (lo * y) % 192;
        for (int hq = lo; hq < hi; hq++) {
            float2 a = Ah[hq*192 + wq];
            float2 e = twsh[m];
            sx += a.x*e.x - a.y*e.y;
            sy += a.x*e.y + a.y*e.x;
            m += y; if (m >= 192) m -= 192;
        }
        Ssh[i][off] = make_float2(sx, sy);
    }
    __syncthreads();
    int col = tid;
    float accre = 0.f;
#pragma unroll
    for (int i = 0; i < 3; i++) {
        int lo = iL[i];
        int wi = iH[i] - lo;
        int m = (lo * col) % 192;
        for (int off = 0; off < wi; off++) {
            float2 S = Ssh[i][off];
            float2 e = twsh[m];
            accre += S.x*e.x - S.y*e.y;
            m += col; if (m >= 192) m -= 192;
        }
    }
    float xfv = accre * (1.0f / 36864.0f);
    float mixv = mixp[0];
    float onem = 1.0f - mixv;
#pragma unroll
    for (int b = 0; b < 4; b++) {
        float s = 0.f;
#pragma unroll
        for (int i = 0; i < 3; i++) {
            const float* xp = x + (b*3 + i)*NPIX;
#pragma unroll
            for (int dy = -1; dy <= 1; dy++) {
                int yq = y + dy;
                if (yq < 0 || yq >= 192) continue;
                const float* rowp = xp + yq*192;
#pragma unroll
                for (int dx = -1; dx <= 1; dx++) {
                    int xq = col + dx;
                    if (xq < 0 || xq >= 192) continue;
                    s += rowp[xq] * cwsh[i*9 + (dy+1)*3 + (dx+1)];
                }
            }
        }
        out[((b*64 + o)*192 + y)*192 + col] = mixv*xfv + onem*s;
    }
}

extern "C" void kernel_launch(void* const* d_in, const int* in_sizes, int n_in,
                              void* d_out, int out_size, void* d_ws, size_t ws_size,
                              hipStream_t stream) {
    const float* x      = (const float*)d_in[0];
    const float* freq   = (const float*)d_in[1];
    const float* theta  = (const float*)d_in[2];
    const float* sigma  = (const float*)d_in[3];
    const float* f0     = (const float*)d_in[4];
    const float* theta0 = (const float*)d_in[5];
    const float* aw1    = (const float*)d_in[6];
    const float* ab1    = (const float*)d_in[7];
    const float* aw2    = (const float*)d_in[8];
    // d_in[9] = attn_b2: cancelled exactly by BN mean-subtraction, unused
    const float* bnw    = (const float*)d_in[10];
    const float* bnb    = (const float*)d_in[11];
    const float* mixp   = (const float*)d_in[12];
    const float* convw  = (const float*)d_in[13];
    const float* fbs    = (const float*)d_in[14];
    float* out = (float*)d_out;
    char* ws = (char*)d_ws;
    if (ws_size < (size_t)WS_FUSED) return;
    int split = ws_size >= (size_t)WS_SPLIT;

    hipMemsetAsync(ws + M2_OFF, 0, 16640, stream);
    k_pre  <<<1, 256, 0, stream>>>(freq, theta, sigma, f0, theta0, fbs,
                                   aw1, ab1, aw2, ws);
    if (split) k_dft1s<<<dim3(12, 48, 2), 192, 0, stream>>>(x, ws);
    else       k_dft1 <<<dim3(12, 48),    192, 0, stream>>>(x, ws);
    k_dft2 <<<dim3(12, 192), 192, 0, stream>>>(ws, split);
    k_stats<<<576, 256, 0, stream>>>(ws);
    k_bn   <<<192, 64, 0, stream>>>(aw2, bnw, bnb, ws);
    k_attn <<<2304, 256, 0, stream>>>(ws);
    if (split) {
        k_ifft <<<dim3(24, 64), 192, 0, stream>>>(ws);
        k_conv <<<dim3(192, 4), 192, 0, stream>>>(x, convw, mixp,
                                                  (const float*)(ws + XF_OFF), out);
    } else {
        k_final<<<dim3(192, 64), 192, 0, stream>>>(x, convw, mixp, out, ws);
    }
}

// Round 8
// 316.795 us; speedup vs baseline: 2.1840x; 1.0729x over previous
//
#include <hip/hip_runtime.h>
#include <math.h>

// Problem constants
#define NPIX  36864            // 192*192
#define PI2   6.28318530717958647692f

// Workspace layout (bytes)
#define TW_OFF    0            // 192 float2 twiddles e^{+2pi i n/192}
#define PCA_OFF   1536         // 576 float4 {a1, lf0, a2, th}
#define PCB_OFF   10752        // 576 float2 {fr, lsc}
#define W1F4_OFF  15360        // 64 float4 {w1[0..2], b1}
#define W2B_OFF   16384        // MFMA B-frags bf16 hi/lo: [kc][t][h][lane][8] = 49152 B
#define BN_OFF    65536        // 192 scale + 192 shift
#define IDX_OFF   67072        // 192*2 ints shifted intervals [o][i]{lo,hi}
#define M2_OFF    68608        // 64*64 M2 + 64 m1 floats (zeroed)
#define T1_OFF    85248        // 12*36864 float2 stage-1 DFT (h-half 0)
#define XS_OFF    3624192      // 12*36864 float2 shifted spectrum
#define AH_OFF    7163136      // 36864 float2 ifftshifted A_tot
#define XF_OFF    7458048      // 64*36864 float xf; ALSO aliased: T1 h-half-1 + E2B
#define E2B_OFF   15846656     // XF_OFF+8MB: 294912 B stage-2 twiddle B-frags
                               // (clobbered by xf later; rebuilt by k_pre each launch)
#define WS_FUSED  7458048
#define WS_SPLIT  16895232

typedef __attribute__((ext_vector_type(8))) short short8;
typedef __attribute__((ext_vector_type(4))) float floatx4;

__device__ __forceinline__ void bf16split(float v, unsigned short& hi, unsigned short& lo) {
    unsigned ub = __builtin_bit_cast(unsigned, v);
    hi = (unsigned short)(ub >> 16);
    float vh = __builtin_bit_cast(float, ub & 0xFFFF0000u);
    lo = (unsigned short)(__builtin_bit_cast(unsigned, v - vh) >> 16);
}

// ---------------- K0: precompute twiddles, params, frag tables, intervals ---
__global__ void k_pre(const float* freq, const float* theta, const float* sigma,
                      const float* f0, const float* theta0, const float* fbs,
                      const float* w1, const float* b1v, const float* w2,
                      char* ws, int split) {
    float2* tw   = (float2*)(ws + TW_OFF);
    float4* pcA  = (float4*)(ws + PCA_OFF);
    float2* pcB  = (float2*)(ws + PCB_OFF);
    float4* w1f4 = (float4*)(ws + W1F4_OFF);
    unsigned short* w2b = (unsigned short*)(ws + W2B_OFF);
    int* idx = (int*)(ws + IDX_OFF);
    int gtid = blockIdx.x * blockDim.x + threadIdx.x;
    int gsz  = gridDim.x * blockDim.x;
    for (int n = gtid; n < 192; n += gsz) {
        float th = PI2 * (float)n / 192.0f;
        tw[n] = make_float2(cosf(th), sinf(th));
    }
    for (int t = gtid; t < 576; t += gsz) {
        int s = t / 192, rem = t % 192, o = rem / 3, i = rem % 3;
        float fr = freq[t], th = theta[t], sg = sigma[t], f0v = f0[t], th0 = theta0[t];
        float lg  = logf(sg / f0v);
        float a1  = -1.0f / (2.0f * lg * lg);
        float lf0 = logf(f0v);
        float a2  = -1.0f / (2.0f * th0 * th0);
        float lsc = -logf(PI2 * sg * sg);          // log(1/(2pi sg^2))
        int pidx = (s*3 + i)*64 + o;
        pcA[pidx] = make_float4(a1, lf0, a2, th);
        pcB[pidx] = make_float2(fr, lsc);
    }
    for (int t = gtid; t < 64; t += gsz)
        w1f4[t] = make_float4(w1[t*3+0], w1[t*3+1], w1[t*3+2], b1v[t]);
    // W2 B-fragments: entry e = ((kc*12+t)*2+h)*64+lane holds 8 bf16 (j=0..7)
    for (int u = gtid; u < 24576; u += gsz) {
        int j = u & 7; int v = u >> 3;
        int l = v & 63; v >>= 6;
        int hsel = v & 1; v >>= 1;
        int t = v % 12; int kc = v / 12;
        int k = kc*32 + (l>>4)*8 + j;
        int c = t*16 + (l & 15);
        float wv = w2[c*64 + k];
        unsigned short hi, lo;
        bf16split(wv, hi, lo);
        w2b[u] = hsel ? lo : hi;
    }
    for (int t = gtid; t < 192; t += gsz) {
        int lo = (int)floorf((fbs[t*2+0] + 1.0f) * 0.5f * 192.0f) - 96;
        int hi = (int)floorf((fbs[t*2+1] + 1.0f) * 0.5f * 192.0f) - 96;
        lo = max(0, min(96, lo));
        hi = max(0, min(96, hi));
        if (hi < lo) hi = lo;
        idx[t*2+0] = lo; idx[t*2+1] = hi;
    }
    // Stage-2 DFT twiddle B-frags (split path only): B_re[k][n], K=384, N=192
    // B_re[2w][n]=cos(2pi w n/192), B_re[2w+1][n]=sin. Layout:
    // offset = ((t*12+kc)*2+half)*512 + lane*8 + j  (shorts)
    if (split) {
        unsigned short* e2b = (unsigned short*)(ws + E2B_OFF);
        for (int u = gtid; u < 147456; u += gsz) {
            int j = u & 7;
            int l = (u >> 3) & 63;
            int half = (u >> 9) & 1;
            int rest = u >> 10;              // t*12 + kc
            int kc = rest % 12, t = rest / 12;
            int k = kc*32 + ((l >> 4) << 3) + j;
            int w = k >> 1, comp = k & 1;
            int n = t*16 + (l & 15);
            int ang = (w * n) % 192;
            float th = PI2 * (float)ang / 192.0f;
            float v = comp ? sinf(th) : cosf(th);
            unsigned short hi, lo;
            bf16split(v, hi, lo);
            e2b[u] = half ? lo : hi;
        }
    }
}

// ---------------- K1s: stage-1 DFT over h, split into 2 h-halves ------------
__global__ __launch_bounds__(192) void k_dft1s(const float* x, char* ws) {
    __shared__ float2 twsh[192];
    const float2* tw = (const float2*)(ws + TW_OFF);
    int tid = threadIdx.x;
    twsh[tid] = tw[tid];
    __syncthreads();
    int bi = blockIdx.x;
    int y0 = blockIdx.y * 4;
    int z  = blockIdx.z;
    float2* t1 = (float2*)(ws + (z ? XF_OFF : T1_OFF));
    int w  = tid;
    const float* xp = x + bi * NPIX;
    float2 acc[4];
#pragma unroll
    for (int d = 0; d < 4; d++) acc[d] = make_float2(0.f, 0.f);
    int h0 = z * 96;
    for (int h = h0; h < h0 + 96; h++) {
        float xv = xp[h*192 + w];
        int m = (h * y0) % 192;
#pragma unroll
        for (int d = 0; d < 4; d++) {
            float2 e = twsh[m];                    // e^{-i th} = (c, -s)
            acc[d].x += xv * e.x;
            acc[d].y -= xv * e.y;
            m += h; if (m >= 192) m -= 192;
        }
    }
    float2* op = t1 + bi * NPIX;
#pragma unroll
    for (int d = 0; d < 4; d++) op[(y0 + d)*192 + w] = acc[d];
}

// ---------------- K1 (fallback, fused path): full-h stage-1 DFT -------------
__global__ __launch_bounds__(192) void k_dft1(const float* x, char* ws) {
    __shared__ float2 twsh[192];
    const float2* tw = (const float2*)(ws + TW_OFF);
    float2* t1 = (float2*)(ws + T1_OFF);
    int tid = threadIdx.x;
    twsh[tid] = tw[tid];
    __syncthreads();
    int bi = blockIdx.x;
    int y0 = blockIdx.y * 4;
    int w  = tid;
    const float* xp = x + bi * NPIX;
    float2 acc[4];
#pragma unroll
    for (int d = 0; d < 4; d++) acc[d] = make_float2(0.f, 0.f);
    for (int h = 0; h < 192; h++) {
        float xv = xp[h*192 + w];
        int m = (h * y0) % 192;
#pragma unroll
        for (int d = 0; d < 4; d++) {
            float2 e = twsh[m];
            acc[d].x += xv * e.x;
            acc[d].y -= xv * e.y;
            m += h; if (m >= 192) m -= 192;
        }
    }
    float2* op = t1 + bi * NPIX;
#pragma unroll
    for (int d = 0; d < 4; d++) op[(y0 + d)*192 + w] = acc[d];
}

// ---------------- K2m: stage-2 DFT as MFMA matmul + fftshift write ----------
// rows = (bi,y) [2304], K = 2*192 (re/im interleaved), N = 192 (kx).
// re = A.B_re ; im = A'.B_re with A'[2w]=ty, A'[2w+1]=-tx (no second B table).
__global__ __launch_bounds__(256) void k_dft2m(char* ws) {
    __shared__ __align__(16) float2 Ar[16][194];
    const float2* t1a = (const float2*)(ws + T1_OFF);
    const float2* t1b = (const float2*)(ws + XF_OFF);
    const unsigned short* e2b = (const unsigned short*)(ws + E2B_OFF);
    float2* Xs = (float2*)(ws + XS_OFF);
    int tid = threadIdx.x;
    int bi = blockIdx.x / 12;
    int y0 = (blockIdx.x % 12) * 16;
    for (int u = tid; u < 3072; u += 256) {
        int m = u / 192, w = u - m*192;
        float2 v = t1a[bi*NPIX + (y0+m)*192 + w];
        float2 v2 = t1b[bi*NPIX + (y0+m)*192 + w];
        v.x += v2.x; v.y += v2.y;
        Ar[m][w] = v;
    }
    __syncthreads();
    int wave = tid >> 6, lane = tid & 63;
    int ml = lane & 15, qd = lane >> 4;
    floatx4 accre[3], accim[3];
#pragma unroll
    for (int tt = 0; tt < 3; tt++) {
        accre[tt] = (floatx4){0.f,0.f,0.f,0.f};
        accim[tt] = (floatx4){0.f,0.f,0.f,0.f};
    }
    union AB { short8 v; unsigned short u[8]; };
#pragma unroll 1
    for (int kc = 0; kc < 12; kc++) {
        int wb = kc*16 + qd*4;
        float4 p01 = *(const float4*)&Ar[ml][wb];
        float4 p23 = *(const float4*)&Ar[ml][wb + 2];
        float av[8]  = {p01.x, p01.y, p01.z, p01.w, p23.x, p23.y, p23.z, p23.w};
        float apv[8] = {p01.y, -p01.x, p01.w, -p01.z, p23.y, -p23.x, p23.w, -p23.z};
        AB ah, al, aph, apl;
#pragma unroll
        for (int j = 0; j < 8; j++) {
            bf16split(av[j],  ah.u[j],  al.u[j]);
            bf16split(apv[j], aph.u[j], apl.u[j]);
        }
#pragma unroll
        for (int tt = 0; tt < 3; tt++) {
            int t = wave*3 + tt;
            const unsigned short* bp = e2b + (((t*12 + kc)*2) << 9) + (lane << 3);
            short8 bh = *(const short8*)bp;
            short8 bl = *(const short8*)(bp + 512);
            floatx4 r = accre[tt];
            r = __builtin_amdgcn_mfma_f32_16x16x32_bf16(ah.v,  bh, r, 0, 0, 0);
            r = __builtin_amdgcn_mfma_f32_16x16x32_bf16(al.v,  bh, r, 0, 0, 0);
            r = __builtin_amdgcn_mfma_f32_16x16x32_bf16(ah.v,  bl, r, 0, 0, 0);
            accre[tt] = r;
            floatx4 q = accim[tt];
            q = __builtin_amdgcn_mfma_f32_16x16x32_bf16(aph.v, bh, q, 0, 0, 0);
            q = __builtin_amdgcn_mfma_f32_16x16x32_bf16(apl.v, bh, q, 0, 0, 0);
            q = __builtin_amdgcn_mfma_f32_16x16x32_bf16(aph.v, bl, q, 0, 0, 0);
            accim[tt] = q;
        }
    }
    int b = bi / 3, i = bi % 3;
    int bs = (b + 2) & 3;
    int is = (i + 1) % 3;
    float2* Xp = Xs + (bs*3 + is)*NPIX;
#pragma unroll
    for (int tt = 0; tt < 3; tt++) {
        int kx = (wave*3 + tt)*16 + ml;
        int ks = kx + 96; if (ks >= 192) ks -= 192;
#pragma unroll
        for (int r = 0; r < 4; r++) {
            int y = y0 + qd*4 + r;
            int ys = y + 96; if (ys >= 192) ys -= 192;
            Xp[ys*192 + ks] = make_float2(accre[tt][r], accim[tt][r]);
        }
    }
}

// ---------------- K2 (fallback, fused path): scalar stage-2 DFT -------------
__global__ __launch_bounds__(192) void k_dft2(char* ws, int split) {
    __shared__ float2 twsh[192];
    __shared__ float2 row[192];
    const float2* tw = (const float2*)(ws + TW_OFF);
    const float2* t1a = (const float2*)(ws + T1_OFF);
    const float2* t1b = (const float2*)(ws + XF_OFF);
    float2* Xs = (float2*)(ws + XS_OFF);
    int tid = threadIdx.x;
    int bi = blockIdx.x, y = blockIdx.y;
    twsh[tid] = tw[tid];
    {
        float2 v = t1a[bi*NPIX + y*192 + tid];
        if (split) {
            float2 v2 = t1b[bi*NPIX + y*192 + tid];
            v.x += v2.x; v.y += v2.y;
        }
        row[tid] = v;
    }
    __syncthreads();
    int kx = tid;
    float2 st = twsh[kx];
    float2 acc = make_float2(0.f, 0.f);
#pragma unroll 1
    for (int w0 = 0; w0 < 192; w0 += 32) {
        float2 e = twsh[(w0 * kx) % 192];
#pragma unroll
        for (int w = 0; w < 32; w++) {
            float2 t = row[w0 + w];
            acc.x += t.x*e.x + t.y*e.y;          // t * conj(e)
            acc.y += t.y*e.x - t.x*e.y;
            float ex = e.x*st.x - e.y*st.y;
            e.y = e.x*st.y + e.y*st.x;
            e.x = ex;
        }
    }
    int b = bi / 3, i = bi % 3;
    int bs = (b + 2) & 3;
    int is = (i + 1) % 3;
    int ys = y + 96;  if (ys >= 192) ys -= 192;
    int ks = kx + 96; if (ks >= 192) ks -= 192;
    Xs[(bs*3 + is)*NPIX + ys*192 + ks] = acc;
}

// ---------------- K3: MFMA SYRK for BN stats: M2 = H1^T H1, m1 = sum(H1) ----
__global__ __launch_bounds__(256) void k_stats(char* ws) {
    __shared__ float magL[192];                    // [s][i] at s*3+i
    __shared__ float4 w1L[64];
    __shared__ float m1L[64];
    __shared__ __align__(16) unsigned short fragH[512*8];  // z*8, z=(kc*4+cb)*64+l
    __shared__ __align__(16) unsigned short fragL[512*8];
    const float2* Xs = (const float2*)(ws + XS_OFF);
    float* M2 = (float*)(ws + M2_OFF);
    int tid = threadIdx.x;
    int wave = tid >> 6, lane = tid & 63;
    if (tid < 64) { w1L[tid] = ((const float4*)(ws + W1F4_OFF))[tid]; m1L[tid] = 0.f; }
    __syncthreads();
    int cch = wave*16 + (lane & 15);               // this thread's channel
    float4 wf = w1L[cch];
    float msum = 0.f;
    floatx4 acc[4];
#pragma unroll
    for (int nb = 0; nb < 4; nb++) acc[nb] = (floatx4){0.f, 0.f, 0.f, 0.f};
    union AB { short8 v; unsigned short u[8]; };
#pragma unroll 1
    for (int it = 0; it < 4; it++) {
        int tile = blockIdx.x * 4 + it;            // 576*4 = 2304 tiles
        int S0 = tile * 64;
        int b = S0 / NPIX;                         // NPIX%64==0 -> const per tile
        int p0 = S0 - b*NPIX;
        if (tid < 192) {
            int i = tid >> 6, s = tid & 63;
            float2 v = Xs[(b*3 + i)*NPIX + p0 + s];
            magL[s*3 + i] = sqrtf(v.x*v.x + v.y*v.y);
        }
        __syncthreads();
#pragma unroll
        for (int kc = 0; kc < 2; kc++) {
            AB h8, l8;
#pragma unroll
            for (int j = 0; j < 8; j++) {
                int s = kc*32 + (lane>>4)*8 + j;
                float mg0 = magL[s*3], mg1 = magL[s*3+1], mg2 = magL[s*3+2];
                float hv = fmaxf(wf.w + wf.x*mg0 + wf.y*mg1 + wf.z*mg2, 0.f);
                msum += hv;
                bf16split(hv, h8.u[j], l8.u[j]);
            }
            int z = (kc*4 + wave)*64 + lane;
            *(short8*)&fragH[z*8] = h8.v;
            *(short8*)&fragL[z*8] = l8.v;
        }
        __syncthreads();
        short8 Ah0 = *(const short8*)&fragH[((0*4+wave)*64 + lane)*8];
        short8 Ah1 = *(const short8*)&fragH[((1*4+wave)*64 + lane)*8];
        short8 Al0 = *(const short8*)&fragL[((0*4+wave)*64 + lane)*8];
        short8 Al1 = *(const short8*)&fragL[((1*4+wave)*64 + lane)*8];
#pragma unroll
        for (int nb = 0; nb < 4; nb++) {
            short8 Bh0 = *(const short8*)&fragH[((0*4+nb)*64 + lane)*8];
            short8 Bh1 = *(const short8*)&fragH[((1*4+nb)*64 + lane)*8];
            short8 Bl0 = *(const short8*)&fragL[((0*4+nb)*64 + lane)*8];
            short8 Bl1 = *(const short8*)&fragL[((1*4+nb)*64 + lane)*8];
            floatx4 a = acc[nb];
            a = __builtin_amdgcn_mfma_f32_16x16x32_bf16(Ah0, Bh0, a, 0, 0, 0);
            a = __builtin_amdgcn_mfma_f32_16x16x32_bf16(Al0, Bh0, a, 0, 0, 0);
            a = __builtin_amdgcn_mfma_f32_16x16x32_bf16(Ah0, Bl0, a, 0, 0, 0);
            a = __builtin_amdgcn_mfma_f32_16x16x32_bf16(Ah1, Bh1, a, 0, 0, 0);
            a = __builtin_amdgcn_mfma_f32_16x16x32_bf16(Al1, Bh1, a, 0, 0, 0);
            a = __builtin_amdgcn_mfma_f32_16x16x32_bf16(Ah1, Bl1, a, 0, 0, 0);
            acc[nb] = a;
        }
        __syncthreads();
    }
#pragma unroll
    for (int nb = 0; nb < 4; nb++)
#pragma unroll
        for (int r = 0; r < 4; r++) {
            int row = wave*16 + (lane>>4)*4 + r;
            int col = nb*16 + (lane & 15);
            atomicAdd(&M2[row*64 + col], acc[nb][r]);
        }
    atomicAdd(&m1L[cch], msum);
    __syncthreads();
    if (tid < 64) atomicAdd(&M2[4096 + tid], m1L[tid]);
}

// ---------------- K4: BN scale/shift, one block per channel -----------------
__global__ __launch_bounds__(64) void k_bn(const float* w2, const float* bnw,
                                           const float* bnb, char* ws) {
    const float* M2 = (const float*)(ws + M2_OFF);
    const float* m1 = M2 + 4096;
    float* bnsc = (float*)(ws + BN_OFF);
    float* bnsh = bnsc + 192;
    int c = blockIdx.x;
    int jj = threadIdx.x;
    const float* row = w2 + c*64;
    float rj = row[jj];
    float inner = 0.f;
    const float* m2r = M2 + jj*64;
    for (int k = 0; k < 64; k++) inner += row[k] * m2r[k];
    float qpart = rj * inner;
    float dpart = rj * m1[jj];
#pragma unroll
    for (int sh = 32; sh >= 1; sh >>= 1) {
        qpart += __shfl_xor(qpart, sh);
        dpart += __shfl_xor(dpart, sh);
    }
    if (jj == 0) {
        const float invN = 1.0f / 147456.0f;
        float d = dpart * invN;
        float qv = qpart * invN;
        float var = qv - d*d;
        float rstd = rsqrtf(var + 1e-5f);
        float scale = bnw[c] * rstd;
        bnsc[c] = scale;
        bnsh[c] = bnb[c] - d * scale;
    }
}

// ---------------- K5: MFMA attention + gabor -> A_tot (online softmax) ------
__global__ __launch_bounds__(256) void k_attn(char* ws) {
    __shared__ __align__(16) char W2L[49152];
    __shared__ float4 w1L[64];
    const float2* Xs = (const float2*)(ws + XS_OFF);
    const float4* pcA4 = (const float4*)(ws + PCA_OFF);
    const float2* pcB2 = (const float2*)(ws + PCB_OFF);
    const float* bnA = (const float*)(ws + BN_OFF);   // [0..192) scale, [192..384) shift
    float2* Ah = (float2*)(ws + AH_OFF);
    int tid = threadIdx.x;
    {
        const float4* s4 = (const float4*)(ws + W2B_OFF);
        float4* d4 = (float4*)W2L;
        for (int u = tid; u < 3072; u += 256) d4[u] = s4[u];
        if (tid < 64) w1L[tid] = ((const float4*)(ws + W1F4_OFF))[tid];
    }
    __syncthreads();
    int wave = tid >> 6, lane = tid & 63;
    int cl = lane & 15, q = lane >> 4;
    int g = blockIdx.x * 4 + wave;
    int pix0 = g * 4;

    union AB { short8 v; unsigned short u[8]; };
    int pb = pix0 + (cl >> 2), bb = cl & 3;
    float2 q0 = Xs[(bb*3+0)*NPIX + pb];
    float2 q1 = Xs[(bb*3+1)*NPIX + pb];
    float2 q2 = Xs[(bb*3+2)*NPIX + pb];
    float mg0 = sqrtf(q0.x*q0.x + q0.y*q0.y);
    float mg1 = sqrtf(q1.x*q1.x + q1.y*q1.y);
    float mg2 = sqrtf(q2.x*q2.x + q2.y*q2.y);
    AB ah[2], al[2];
#pragma unroll
    for (int kc = 0; kc < 2; kc++)
#pragma unroll
        for (int j = 0; j < 8; j++) {
            int k = kc*32 + q*8 + j;
            float4 wf = w1L[k];
            float hv = fmaxf(wf.w + wf.x*mg0 + wf.y*mg1 + wf.z*mg2, 0.f);
            bf16split(hv, ah[kc].u[j], al[kc].u[j]);
        }
    int pixE = pix0 + q;
    int hh = pixE / 192, ww = pixE - hh*192;
    float yy = -1.0f + (float)hh * (2.0f/191.0f);
    float xx = -1.0f + (float)ww * (2.0f/191.0f);
    float rr = sqrtf(xx*xx + yy*yy + 1e-6f);
    float lr = __logf(rr);
    float phi = atan2f(yy, xx);
    float sm0 = 0.f, sm1 = 0.f, sm2 = 0.f, sm3 = 0.f;
    float Wr[4][3];
#pragma unroll
    for (int r = 0; r < 4; r++) { Wr[r][0] = 0.f; Wr[r][1] = 0.f; Wr[r][2] = 0.f; }
#pragma unroll 2
    for (int t = 0; t < 12; t++) {
        floatx4 a = {0.f, 0.f, 0.f, 0.f};
#pragma unroll
        for (int kc = 0; kc < 2; kc++) {
            int ob = (((kc*12 + t)*2)*64 + lane)*16;
            short8 bh = *(const short8*)(W2L + ob);
            short8 bl = *(const short8*)(W2L + ob + 1024);
            a = __builtin_amdgcn_mfma_f32_16x16x32_bf16(ah[kc].v, bh, a, 0, 0, 0);
            a = __builtin_amdgcn_mfma_f32_16x16x32_bf16(al[kc].v, bh, a, 0, 0, 0);
            a = __builtin_amdgcn_mfma_f32_16x16x32_bf16(ah[kc].v, bl, a, 0, 0, 0);
        }
        int c = t*16 + cl;
        float sc_ = bnA[c], sh_ = bnA[192 + c];
        float e0 = __expf(a[0]*sc_ + sh_);
        float e1 = __expf(a[1]*sc_ + sh_);
        float e2 = __expf(a[2]*sc_ + sh_);
        float e3 = __expf(a[3]*sc_ + sh_);
        sm0 += e0; sm1 += e1; sm2 += e2; sm3 += e3;
        int sB = c >> 6, o = c & 63;
#pragma unroll
        for (int i = 0; i < 3; i++) {
            int pidx = (sB*3 + i)*64 + o;
            float4 pa = pcA4[pidx];
            float2 pbv = pcB2[pidx];
            float dl = lr - pa.y, dp = phi - pa.w;
            float gv = __expf(pa.x*dl*dl + pa.z*dp*dp + pbv.y) * __cosf(pbv.x*rr);
            Wr[0][i] += e0*gv; Wr[1][i] += e1*gv;
            Wr[2][i] += e2*gv; Wr[3][i] += e3*gv;
        }
    }
#pragma unroll
    for (int sh = 1; sh < 16; sh <<= 1) {
        sm0 += __shfl_xor(sm0, sh); sm1 += __shfl_xor(sm1, sh);
        sm2 += __shfl_xor(sm2, sh); sm3 += __shfl_xor(sm3, sh);
    }
    float inv0 = 1.0f/sm0, inv1 = 1.0f/sm1, inv2 = 1.0f/sm2, inv3 = 1.0f/sm3;
    float are = 0.f, aim = 0.f;
#pragma unroll
    for (int i = 0; i < 3; i++) {
        float2 x0 = Xs[(0*3+i)*NPIX + pixE];
        float2 x1 = Xs[(1*3+i)*NPIX + pixE];
        float2 x2 = Xs[(2*3+i)*NPIX + pixE];
        float2 x3 = Xs[(3*3+i)*NPIX + pixE];
        float w0v = Wr[0][i]*inv0, w1v = Wr[1][i]*inv1;
        float w2v = Wr[2][i]*inv2, w3v = Wr[3][i]*inv3;
        are += w0v*x0.x + w1v*x1.x + w2v*x2.x + w3v*x3.x;
        aim += w0v*x0.y + w1v*x1.y + w2v*x2.y + w3v*x3.y;
    }
#pragma unroll
    for (int sh = 1; sh < 16; sh <<= 1) {
        are += __shfl_xor(are, sh);
        aim += __shfl_xor(aim, sh);
    }
    if (cl == 0) {
        int hs = hh + 96; if (hs >= 192) hs -= 192;
        int wsx = ww + 96; if (wsx >= 192) wsx -= 192;
        Ah[hs*192 + wsx] = make_float2(are, aim);
    }
}

// ---------------- K6a: interval-masked IDFT -> xf, 8 rows / 384 threads -----
// Ssh layout [i][off][yy]: phase-B reads are 2x float4 broadcasts; phase B
// split into 2 col-groups (4 yy each). NOTE: 192 is not pow2 -> no & masks!
__global__ __launch_bounds__(384) void k_ifft(char* ws) {
    __shared__ float2 twsh[192];
    __shared__ __align__(16) float2 Ssh[3][96][8];
    __shared__ int iL[3], iH[3];
    const float2* tw = (const float2*)(ws + TW_OFF);
    const int* idx = (const int*)(ws + IDX_OFF);
    const float2* Ah = (const float2*)(ws + AH_OFF);
    float* xf = (float*)(ws + XF_OFF);
    int tid = threadIdx.x;
    int y0 = blockIdx.x * 8;
    int o = blockIdx.y;
    int op = (o + 32) & 63;
    if (tid < 192) twsh[tid] = tw[tid];
    if (tid < 3) { iL[tid] = idx[(op*3 + tid)*2]; iH[tid] = idx[(op*3 + tid)*2 + 1]; }
    __syncthreads();
    int n0 = iH[0]-iL[0], n1 = iH[1]-iL[1], n2 = iH[2]-iL[2];
    int p1 = n0 + n1, T = p1 + n2;
    // Phase A: tgt = (task, y-pair); each handles 2 consecutive y
    for (int tgt = tid; tgt < 4*T; tgt += 384) {
        int task = tgt >> 2, yp = tgt & 3;
        int i, off, lo, hi;
        if (task < n0)      { i = 0; off = task;      lo = iL[0]; hi = iH[0]; }
        else if (task < p1) { i = 1; off = task - n0; lo = iL[1]; hi = iH[1]; }
        else                { i = 2; off = task - p1; lo = iL[2]; hi = iH[2]; }
        int wq = lo + off;
        int ya = y0 + yp*2, yb = ya + 1;
        float2 ea = twsh[(lo * ya) % 192], sta = twsh[ya];
        float2 eb = twsh[(lo * yb) % 192], stb = twsh[yb];
        float2 Sa = make_float2(0.f, 0.f), Sb = make_float2(0.f, 0.f);
        for (int hq = lo; hq < hi; hq++) {
            float2 a = Ah[hq*192 + wq];
            Sa.x += a.x*ea.x - a.y*ea.y;
            Sa.y += a.x*ea.y + a.y*ea.x;
            float ex = ea.x*sta.x - ea.y*sta.y;
            ea.y = ea.x*sta.y + ea.y*sta.x; ea.x = ex;
            Sb.x += a.x*eb.x - a.y*eb.y;
            Sb.y += a.x*eb.y + a.y*eb.x;
            ex = eb.x*stb.x - eb.y*stb.y;
            eb.y = eb.x*stb.y + eb.y*stb.x; eb.x = ex;
        }
        *(float4*)&Ssh[i][off][yp*2] = make_float4(Sa.x, Sa.y, Sb.x, Sb.y);
    }
    __syncthreads();
    // Phase B: thread = (col, y-half of 4); broadcast float4 reads.
    // BUGFIX (r6/r7): tid & 191 != tid % 192 (192 not pow2) -> explicit split.
    int yh  = (tid < 192) ? 0 : 1;
    int col = (tid < 192) ? tid : (tid - 192);
    float2 stepc = twsh[col];
    float acc0 = 0.f, acc1 = 0.f, acc2 = 0.f, acc3 = 0.f;
#pragma unroll
    for (int i = 0; i < 3; i++) {
        int lo = iL[i];
        int wi = iH[i] - lo;
        float2 e = twsh[(lo * col) % 192];
        for (int off = 0; off < wi; off++) {
            float4 s01 = *(const float4*)&Ssh[i][off][yh*4];
            float4 s23 = *(const float4*)&Ssh[i][off][yh*4 + 2];
            acc0 += s01.x*e.x - s01.y*e.y;
            acc1 += s01.z*e.x - s01.w*e.y;
            acc2 += s23.x*e.x - s23.y*e.y;
            acc3 += s23.z*e.x - s23.w*e.y;
            float ex = e.x*stepc.x - e.y*stepc.y;
            e.y = e.x*stepc.y + e.y*stepc.x;
            e.x = ex;
        }
    }
    float* xp = xf + o*NPIX + (y0 + yh*4)*192 + col;
    const float s = 1.0f / 36864.0f;
    xp[0]     = acc0 * s;
    xp[192]   = acc1 * s;
    xp[384]   = acc2 * s;
    xp[576]   = acc3 * s;
}

// ---------------- K6b: 3x3 conv (sgpr weights) + mix (split path) -----------
__global__ __launch_bounds__(192) void k_conv(const float* x, const float* convw,
                                              const float* mixp, const float* xf,
                                              float* out) {
    int col = threadIdx.x;
    int y = blockIdx.x;
    int b = blockIdx.y;
    float xv[27];
#pragma unroll
    for (int i = 0; i < 3; i++)
#pragma unroll
        for (int dy = 0; dy < 3; dy++)
#pragma unroll
            for (int dx = 0; dx < 3; dx++) {
                int yq = y + dy - 1, xq = col + dx - 1;
                bool ok = (yq >= 0) & (yq < 192) & (xq >= 0) & (xq < 192);
                xv[(i*3 + dy)*3 + dx] = ok ? x[(b*3+i)*NPIX + yq*192 + xq] : 0.f;
            }
    float mixv = mixp[0];
    float onem = 1.0f - mixv;
    for (int o = 0; o < 64; o++) {
        float s = 0.f;
#pragma unroll
        for (int c = 0; c < 27; c++) s += xv[c] * convw[o*27 + c];
        float xfv = xf[o*NPIX + y*192 + col];
        out[((b*64 + o)*192 + y)*192 + col] = mixv*xfv + onem*s;
    }
}

// ---------------- K6 (fallback): fused IDFT + conv + mix --------------------
__global__ __launch_bounds__(192) void k_final(const float* x, const float* convw,
                                               const float* mixp, float* out, char* ws) {
    __shared__ float2 twsh[192];
    __shared__ float2 Ssh[3][96];
    __shared__ float cwsh[27];
    __shared__ int iL[3], iH[3];
    const float2* tw = (const float2*)(ws + TW_OFF);
    const int* idx = (const int*)(ws + IDX_OFF);
    const float2* Ah = (const float2*)(ws + AH_OFF);
    int tid = threadIdx.x;
    int y = blockIdx.x;
    int o = blockIdx.y;
    int op = (o + 32) & 63;
    twsh[tid] = tw[tid];
    if (tid < 27) cwsh[tid] = convw[o*27 + tid];
    if (tid < 3) { iL[tid] = idx[(op*3 + tid)*2]; iH[tid] = idx[(op*3 + tid)*2 + 1]; }
    __syncthreads();
    int l0 = iL[0], u0 = iH[0], l1 = iL[1], u1 = iH[1], l2 = iL[2], u2 = iH[2];
    int n0 = u0 - l0, n1 = u1 - l1, n2 = u2 - l2;
    int p1 = n0 + n1, T = p1 + n2;
    for (int t = tid; t < T; t += 192) {
        int i, off, lo, hi;
        if (t < n0)      { i = 0; off = t;      lo = l0; hi = u0; }
        else if (t < p1) { i = 1; off = t - n0; lo = l1; hi = u1; }
        else             { i = 2; off = t - p1; lo = l2; hi = u2; }
        int wq = lo + off;
        float sx = 0.f, sy = 0.f;
        int m = (lo * y) % 192;
        for (int hq = lo; hq < hi; hq++) {
            float2 a = Ah[hq*192 + wq];
            float2 e = twsh[m];
            sx += a.x*e.x - a.y*e.y;
            sy += a.x*e.y + a.y*e.x;
            m += y; if (m >= 192) m -= 192;
        }
        Ssh[i][off] = make_float2(sx, sy);
    }
    __syncthreads();
    int col = tid;
    float accre = 0.f;
#pragma unroll
    for (int i = 0; i < 3; i++) {
        int lo = iL[i];
        int wi = iH[i] - lo;
        int m = (lo * col) % 192;
        for (int off = 0; off < wi; off++) {
            float2 S = Ssh[i][off];
            float2 e = twsh[m];
            accre += S.x*e.x - S.y*e.y;
            m += col; if (m >= 192) m -= 192;
        }
    }
    float xfv = accre * (1.0f / 36864.0f);
    float mixv = mixp[0];
    float onem = 1.0f - mixv;
#pragma unroll
    for (int b = 0; b < 4; b++) {
        float s = 0.f;
#pragma unroll
        for (int i = 0; i < 3; i++) {
            const float* xp = x + (b*3 + i)*NPIX;
#pragma unroll
            for (int dy = -1; dy <= 1; dy++) {
                int yq = y + dy;
                if (yq < 0 || yq >= 192) continue;
                const float* rowp = xp + yq*192;
#pragma unroll
                for (int dx = -1; dx <= 1; dx++) {
                    int xq = col + dx;
                    if (xq < 0 || xq >= 192) continue;
                    s += rowp[xq] * cwsh[i*9 + (dy+1)*3 + (dx+1)];
                }
            }
        }
        out[((b*64 + o)*192 + y)*192 + col] = mixv*xfv + onem*s;
    }
}

extern "C" void kernel_launch(void* const* d_in, const int* in_sizes, int n_in,
                              void* d_out, int out_size, void* d_ws, size_t ws_size,
                              hipStream_t stream) {
    const float* x      = (const float*)d_in[0];
    const float* freq   = (const float*)d_in[1];
    const float* theta  = (const float*)d_in[2];
    const float* sigma  = (const float*)d_in[3];
    const float* f0     = (const float*)d_in[4];
    const float* theta0 = (const float*)d_in[5];
    const float* aw1    = (const float*)d_in[6];
    const float* ab1    = (const float*)d_in[7];
    const float* aw2    = (const float*)d_in[8];
    // d_in[9] = attn_b2: cancelled exactly by BN mean-subtraction, unused
    const float* bnw    = (const float*)d_in[10];
    const float* bnb    = (const float*)d_in[11];
    const float* mixp   = (const float*)d_in[12];
    const float* convw  = (const float*)d_in[13];
    const float* fbs    = (const float*)d_in[14];
    float* out = (float*)d_out;
    char* ws = (char*)d_ws;
    if (ws_size < (size_t)WS_FUSED) return;
    int split = ws_size >= (size_t)WS_SPLIT;

    hipMemsetAsync(ws + M2_OFF, 0, 16640, stream);
    k_pre  <<<8, 256, 0, stream>>>(freq, theta, sigma, f0, theta0, fbs,
                                   aw1, ab1, aw2, ws, split);
    if (split) {
        k_dft1s<<<dim3(12, 48, 2), 192, 0, stream>>>(x, ws);
        k_dft2m<<<144, 256, 0, stream>>>(ws);
    } else {
        k_dft1 <<<dim3(12, 48), 192, 0, stream>>>(x, ws);
        k_dft2 <<<dim3(12, 192), 192, 0, stream>>>(ws, 0);
    }
    k_stats<<<576, 256, 0, stream>>>(ws);
    k_bn   <<<192, 64, 0, stream>>>(aw2, bnw, bnb, ws);
    k_attn <<<2304, 256, 0, stream>>>(ws);
    if (split) {
        k_ifft <<<dim3(24, 64), 384, 0, stream>>>(ws);
        k_conv <<<dim3(192, 4), 192, 0, stream>>>(x, convw, mixp,
                                                  (const float*)(ws + XF_OFF), out);
    } else {
        k_final<<<dim3(192, 64), 192, 0, stream>>>(x, convw, mixp, out, ws);
    }
}